// Round 6
// baseline (598.405 us; speedup 1.0000x reference)
//
#include <hip/hip_runtime.h>

#define NN 50000
#define NE 800000
#define DDIM 64
#define PADX 68          // fp32 LDS row stride (node pool)
#define PADS 68          // fp32 per-wave scratch stride (rows are 272 B -> 16B aligned, odd*4 banks)
#define NB_SCAN ((NN + 255) / 256)   // 196
#define NEG_SLOPE 0.2f
#define EPS_V 1e-5f

typedef short bf16x8 __attribute__((ext_vector_type(8)));
typedef float f32x4 __attribute__((ext_vector_type(4)));

__device__ __forceinline__ float lrelu_f(float x) { return x >= 0.0f ? x : NEG_SLOPE * x; }

__device__ __forceinline__ unsigned short bf16_rn(float x) {
    union { float f; unsigned int u; } c; c.f = x;
    unsigned int r = c.u + 0x7FFF + ((c.u >> 16) & 1);
    return (unsigned short)(r >> 16);
}
__device__ __forceinline__ float bf16_tof(unsigned short h) {
    union { float f; unsigned int u; } c; c.u = ((unsigned int)h) << 16;
    return c.f;
}

// packed bf16 convert (RNE), 2 f32 -> u32 [lo=bf16(a) | hi=bf16(b)]
__device__ __forceinline__ unsigned cvtpk_bf16(float a, float b) {
    unsigned r;
    asm("v_cvt_pk_bf16_f32 %0, %1, %2" : "=v"(r) : "v"(a), "v"(b));
    return r;
}

// split 8 fp32 -> hi/lo bf16x8 (RNE both; ~2^-18 effective rel err) via v_cvt_pk_bf16_f32
__device__ __forceinline__ void split8(const float* __restrict__ v, bf16x8& h, bf16x8& l)
{
    union { bf16x8 v8; unsigned u[4]; } H, L;
    #pragma unroll
    for (int k = 0; k < 4; ++k) {
        float a = v[2*k], b = v[2*k+1];
        unsigned p = cvtpk_bf16(a, b);
        union { float f; unsigned u; } h0, h1;
        h0.u = p << 16;
        h1.u = p & 0xFFFF0000u;
        unsigned q = cvtpk_bf16(a - h0.f, b - h1.f);
        H.u[k] = p;
        L.u[k] = q;
    }
    h = H.v8; l = L.v8;
}

// ---------------- fp32 micro-tile GEMM helpers (node pooling only) ----------------
__device__ __forceinline__ void mma_tile(float acc[16], const float* __restrict__ XT,
                                         const float* __restrict__ Wc, int e0, int f0)
{
    #pragma unroll 4
    for (int kk = 0; kk < DDIM; kk += 4) {
        float4 A0 = *(const float4*)&XT[(kk+0)*PADX + e0];
        float4 A1 = *(const float4*)&XT[(kk+1)*PADX + e0];
        float4 A2 = *(const float4*)&XT[(kk+2)*PADX + e0];
        float4 A3 = *(const float4*)&XT[(kk+3)*PADX + e0];
        float4 B0 = *(const float4*)&Wc[(f0+0)*PADX + kk];
        float4 B1 = *(const float4*)&Wc[(f0+1)*PADX + kk];
        float4 B2 = *(const float4*)&Wc[(f0+2)*PADX + kk];
        float4 B3 = *(const float4*)&Wc[(f0+3)*PADX + kk];
        const float a[4][4] = {{A0.x,A0.y,A0.z,A0.w},{A1.x,A1.y,A1.z,A1.w},
                               {A2.x,A2.y,A2.z,A2.w},{A3.x,A3.y,A3.z,A3.w}};
        const float b[4][4] = {{B0.x,B0.y,B0.z,B0.w},{B1.x,B1.y,B1.z,B1.w},
                               {B2.x,B2.y,B2.z,B2.w},{B3.x,B3.y,B3.z,B3.w}};
        #pragma unroll
        for (int j = 0; j < 4; ++j)
            #pragma unroll
            for (int i = 0; i < 4; ++i)
                #pragma unroll
                for (int q = 0; q < 4; ++q)
                    acc[i*4+j] = fmaf(a[q][i], b[j][q], acc[i*4+j]);
    }
}

__device__ __forceinline__ void load_w_f32(float* __restrict__ Wc, const float* __restrict__ Wg, int tid)
{
    #pragma unroll
    for (int c = 0; c < 4; ++c) {
        int idx = (c << 10) + (tid << 2);
        int f = idx >> 6, k = idx & 63;
        *(float4*)&Wc[f*PADX + k] = *(const float4*)&Wg[idx];
    }
}

// ---------------- node pooling (fp32) + fused dst histogram ----------------
__global__ __launch_bounds__(256, 3)
void node_pool_kernel(const float* __restrict__ V,
                      const float* __restrict__ Aw, const float* __restrict__ Ab,
                      const float* __restrict__ Bw, const float* __restrict__ Bbv,
                      float* __restrict__ Vp,
                      const int* __restrict__ dst, int* __restrict__ degi)
{
    __shared__ float Wc[DDIM*PADX];
    __shared__ float XT[DDIM*PADX];
    const int tid = threadIdx.x;
    const int nb = blockIdx.x * 64;
    const int e0 = (tid & 15) << 2;
    const int f0 = (tid >> 4) << 2;

    #pragma unroll
    for (int c = 0; c < 4; ++c) {
        int idx = (c << 10) + (tid << 2);
        int e = idx >> 6, d = idx & 63;
        int row = nb + e; if (row > NN-1) row = NN-1;
        float4 v = *(const float4*)&V[(size_t)row*DDIM + d];
        XT[(d+0)*PADX + e] = lrelu_f(v.x);
        XT[(d+1)*PADX + e] = lrelu_f(v.y);
        XT[(d+2)*PADX + e] = lrelu_f(v.z);
        XT[(d+3)*PADX + e] = lrelu_f(v.w);
    }
    load_w_f32(Wc, Aw, tid);
    __syncthreads();

    float acc[16];
    #pragma unroll
    for (int i = 0; i < 16; ++i) acc[i] = 0.f;
    mma_tile(acc, XT, Wc, e0, f0);
    __syncthreads();

    {   // lrelu(acc + Ab) -> XT
        float4 bv = *(const float4*)&Ab[f0];
        const float ba[4] = {bv.x, bv.y, bv.z, bv.w};
        #pragma unroll
        for (int j = 0; j < 4; ++j) {
            float4 v;
            v.x = lrelu_f(acc[0*4+j] + ba[j]);
            v.y = lrelu_f(acc[1*4+j] + ba[j]);
            v.z = lrelu_f(acc[2*4+j] + ba[j]);
            v.w = lrelu_f(acc[3*4+j] + ba[j]);
            *(float4*)&XT[(f0+j)*PADX + e0] = v;
        }
    }
    load_w_f32(Wc, Bw, tid);
    __syncthreads();

    float acc2[16];
    #pragma unroll
    for (int i = 0; i < 16; ++i) acc2[i] = 0.f;
    mma_tile(acc2, XT, Wc, e0, f0);

    float4 bv = *(const float4*)&Bbv[f0];
    #pragma unroll
    for (int i = 0; i < 4; ++i) {
        int row = nb + e0 + i;
        if (row < NN) {
            float4 o;
            o.x = acc2[i*4+0] + bv.x;
            o.y = acc2[i*4+1] + bv.y;
            o.z = acc2[i*4+2] + bv.z;
            o.w = acc2[i*4+3] + bv.w;
            *(float4*)&Vp[(size_t)row*DDIM + f0] = o;
        }
    }

    // fused histogram tail: grid-stride over edges
    const int stride = gridDim.x * 256;
    for (int e = blockIdx.x * 256 + tid; e < NE; e += stride)
        atomicAdd(&degi[dst[e]], 1);
}

// ---------------- split-bf16 weight fragment precompute ----------------
// Layout: WF[L][t][ks][hl][lane][j] shorts; per-layer stride 8192 shorts.
// lane: n=lane&15 (feature col), kg=lane>>4; f=t*16+n; k=ks*32+kg*8+j.
__global__ __launch_bounds__(256)
void prep_w_kernel(const float* __restrict__ W1, const float* __restrict__ W2,
                   const float* __restrict__ WB, const float* __restrict__ WC,
                   short* __restrict__ WF)
{
    int gid = blockIdx.x * 256 + threadIdx.x;   // grid = 64 blocks -> 16384 threads
    int L = gid >> 12, r = gid & 4095;
    int t = r >> 10, ks = (r >> 9) & 1, lane = (r >> 3) & 63, j = r & 7;
    const float* Ws = (L == 0) ? W1 : (L == 1) ? W2 : (L == 2) ? WB : WC;
    int n = lane & 15, kg = lane >> 4;
    int f = t*16 + n, k = ks*32 + kg*8 + j;
    float v = Ws[f*64 + k];
    unsigned short h = bf16_rn(v);
    unsigned short l = bf16_rn(v - bf16_tof(h));
    int base = L*8192 + ((t*2 + ks)*2)*512 + lane*8 + j;
    WF[base]       = (short)h;
    WF[base + 512] = (short)l;
}

// ---------------- CSR build: scan / scatter ----------------
__global__ __launch_bounds__(256)
void scan1_kernel(const int* __restrict__ degi, int* __restrict__ linc, int* __restrict__ bsum)
{
    __shared__ int ws[4];
    const int tid = threadIdx.x;
    const int lane = tid & 63, wv = tid >> 6;
    int i = blockIdx.x * 256 + tid;
    int v = (i < NN) ? degi[i] : 0;
    int sc = v;
    #pragma unroll
    for (int off = 1; off < 64; off <<= 1) {
        int t = __shfl_up(sc, off, 64);
        if (lane >= off) sc += t;
    }
    if (lane == 63) ws[wv] = sc;
    __syncthreads();
    int wb = 0;
    #pragma unroll
    for (int w = 0; w < 4; ++w) if (w < wv) wb += ws[w];
    int incl = sc + wb;
    if (i < NN) linc[i] = incl;
    if (tid == 255) bsum[blockIdx.x] = incl;
}

__global__ __launch_bounds__(256)
void scan23_kernel(const int* __restrict__ degi, const int* __restrict__ linc,
                   const int* __restrict__ bsum, int* __restrict__ curs)
{
    __shared__ int ws[4];
    __shared__ int base_s;
    const int tid = threadIdx.x;
    const int lane = tid & 63, wv = tid >> 6;
    int v = (tid < NB_SCAN) ? bsum[tid] : 0;
    int sc = v;
    #pragma unroll
    for (int off = 1; off < 64; off <<= 1) {
        int t = __shfl_up(sc, off, 64);
        if (lane >= off) sc += t;
    }
    if (lane == 63) ws[wv] = sc;
    __syncthreads();
    int wb = 0;
    #pragma unroll
    for (int w = 0; w < 4; ++w) if (w < wv) wb += ws[w];
    if (tid == blockIdx.x) base_s = sc + wb - v;
    __syncthreads();
    int i = blockIdx.x * 256 + tid;
    if (i < NN) curs[i] = base_s + linc[i] - degi[i];
}

// scatter: compute inverse permutation pinv[e] = sorted position of edge e.
// After this kernel, curs[n] = global END offset of node n's segment.
__global__ __launch_bounds__(256)
void scatter_kernel(const int* __restrict__ dst, int* __restrict__ cursor, int* __restrict__ pinv)
{
    int e = blockIdx.x * 256 + threadIdx.x;
    if (e < NE) {
        pinv[e] = atomicAdd(&cursor[dst[e]], 1);
    }
}

// ---------------- natural-order split-bf16 MFMA edge MLP + message ----------------
// Dual-tile GEMM: weight fragments loaded ONCE per (ks) serve both 16-row tiles.
__device__ __forceinline__ void gemm64_dual(const short* __restrict__ WL, int lane,
                                            const bf16x8 ah0[2], const bf16x8 al0[2],
                                            const bf16x8 ah1[2], const bf16x8 al1[2],
                                            f32x4 acc0[4], f32x4 acc1[4])
{
    #pragma unroll
    for (int ks = 0; ks < 2; ++ks) {
        bf16x8 bh[4], bl[4];
        #pragma unroll
        for (int t = 0; t < 4; ++t) {
            bh[t] = *(const bf16x8*)&WL[(((t*2 + ks)*2 + 0)*64 + lane)*8];
            bl[t] = *(const bf16x8*)&WL[(((t*2 + ks)*2 + 1)*64 + lane)*8];
        }
        #pragma unroll
        for (int t = 0; t < 4; ++t) {
            acc0[t] = __builtin_amdgcn_mfma_f32_16x16x32_bf16(al0[ks], bh[t], acc0[t], 0, 0, 0);
            acc1[t] = __builtin_amdgcn_mfma_f32_16x16x32_bf16(al1[ks], bh[t], acc1[t], 0, 0, 0);
            acc0[t] = __builtin_amdgcn_mfma_f32_16x16x32_bf16(ah0[ks], bl[t], acc0[t], 0, 0, 0);
            acc1[t] = __builtin_amdgcn_mfma_f32_16x16x32_bf16(ah1[ks], bl[t], acc1[t], 0, 0, 0);
            acc0[t] = __builtin_amdgcn_mfma_f32_16x16x32_bf16(ah0[ks], bh[t], acc0[t], 0, 0, 0);
            acc1[t] = __builtin_amdgcn_mfma_f32_16x16x32_bf16(ah1[ks], bh[t], acc1[t], 0, 0, 0);
        }
    }
}

// Single-tile GEMM (heads phase; halves live accumulator pressure)
__device__ __forceinline__ void gemm64(const short* __restrict__ WL, int lane,
                                       const bf16x8 ah[2], const bf16x8 al[2], f32x4 acc[4])
{
    #pragma unroll
    for (int ks = 0; ks < 2; ++ks) {
        bf16x8 bh[4], bl[4];
        #pragma unroll
        for (int t = 0; t < 4; ++t) {
            bh[t] = *(const bf16x8*)&WL[(((t*2 + ks)*2 + 0)*64 + lane)*8];
            bl[t] = *(const bf16x8*)&WL[(((t*2 + ks)*2 + 1)*64 + lane)*8];
        }
        #pragma unroll
        for (int t = 0; t < 4; ++t) {
            acc[t] = __builtin_amdgcn_mfma_f32_16x16x32_bf16(al[ks], bh[t], acc[t], 0, 0, 0);
            acc[t] = __builtin_amdgcn_mfma_f32_16x16x32_bf16(ah[ks], bl[t], acc[t], 0, 0, 0);
            acc[t] = __builtin_amdgcn_mfma_f32_16x16x32_bf16(ah[ks], bh[t], acc[t], 0, 0, 0);
        }
    }
}

// Single-tile transpose through a 16-row per-wave LDS tile (reused sequentially;
// per-wave LDS ops are in-order, wave_barrier fences compiler reordering).
__device__ __forceinline__ void transpose_frags(float* __restrict__ sw, const f32x4 y[4],
                                                int lane, bf16x8 ah[2], bf16x8 al[2])
{
    const int n = lane & 15, mg = lane >> 4;
    #pragma unroll
    for (int t = 0; t < 4; ++t)
        #pragma unroll
        for (int r = 0; r < 4; ++r)
            sw[(mg*4 + r)*PADS + t*16 + n] = y[t][r];
    __builtin_amdgcn_wave_barrier();
    const int m = lane & 15, kg = lane >> 4;   // m: edge row, kg: k-group
    float x[16];
    *(float4*)&x[0]  = *(const float4*)&sw[m*PADS + kg*8];
    *(float4*)&x[4]  = *(const float4*)&sw[m*PADS + kg*8 + 4];
    *(float4*)&x[8]  = *(const float4*)&sw[m*PADS + 32 + kg*8];
    *(float4*)&x[12] = *(const float4*)&sw[m*PADS + 32 + kg*8 + 4];
    split8(&x[0], ah[0], al[0]);
    split8(&x[8], ah[1], al[1]);
    __builtin_amdgcn_wave_barrier();
}

// E1: natural edge order. Coalesced E reads, MLP+heads+message, write message row
// to its dst-sorted position pinv[e]. No atomics, no eidx gather.
// Register-pressure shaped: heads computed per-tile (acc peak 32 not 64), 16-row LDS.
__global__ __launch_bounds__(256, 4)
void e1_mlp_kernel(const float* __restrict__ Eg,
                   const int* __restrict__ src, const int* __restrict__ pinv,
                   const short* __restrict__ WF,
                   const float* __restrict__ b1, const float* __restrict__ b2,
                   const float* __restrict__ bB, const float* __restrict__ bC,
                   const float* __restrict__ Vp,
                   float* __restrict__ M1s)
{
    __shared__ float scratch[4 * 16 * PADS];   // per-wave 16x68 fp32 tile (17408 B)
    __shared__ int aux[4 * 64];                // per-wave: [0..31]=pinv, [32..63]=src

    const int tid = threadIdx.x;
    const int lane = tid & 63, wv = tid >> 6;
    float* sw = scratch + wv * 16 * PADS;
    int* auxw = aux + wv * 64;

    const int e0 = blockIdx.x * 128 + wv * 32;  // this wave's 32 edges (natural order)
    const int m = lane & 15, kg = lane >> 4;
    const int n = lane & 15, mg = lane >> 4;

    if (lane < 32) {
        auxw[lane]      = pinv[e0 + lane];
        auxw[32 + lane] = src[e0 + lane];
    }
    // A-fragments straight from CONSECUTIVE E rows (streaming, no gather)
    bf16x8 ah0[2], al0[2], ah1[2], al1[2];
    {
        const float* er0 = Eg + (size_t)(e0 + m)*DDIM + kg*8;
        const float* er1 = Eg + (size_t)(e0 + 16 + m)*DDIM + kg*8;
        float x[16];
        *(float4*)&x[0]  = *(const float4*)&er0[0];
        *(float4*)&x[4]  = *(const float4*)&er0[4];
        *(float4*)&x[8]  = *(const float4*)&er0[32];
        *(float4*)&x[12] = *(const float4*)&er0[36];
        split8(&x[0], ah0[0], al0[0]);
        split8(&x[8], ah0[1], al0[1]);
        *(float4*)&x[0]  = *(const float4*)&er1[0];
        *(float4*)&x[4]  = *(const float4*)&er1[4];
        *(float4*)&x[8]  = *(const float4*)&er1[32];
        *(float4*)&x[12] = *(const float4*)&er1[36];
        split8(&x[0], ah1[0], al1[0]);
        split8(&x[8], ah1[1], al1[1]);
    }

    // layer 1 (dual-tile: B-frags loaded once for both tiles)
    f32x4 acc0[4], acc1[4];
    #pragma unroll
    for (int t = 0; t < 4; ++t) { acc0[t] = (f32x4){0.f,0.f,0.f,0.f}; acc1[t] = (f32x4){0.f,0.f,0.f,0.f}; }
    gemm64_dual(WF, lane, ah0, al0, ah1, al1, acc0, acc1);
    #pragma unroll
    for (int t = 0; t < 4; ++t) {
        float b = b1[t*16 + n];
        #pragma unroll
        for (int r = 0; r < 4; ++r) {
            acc0[t][r] = fmaxf(acc0[t][r] + b, 0.0f);
            acc1[t][r] = fmaxf(acc1[t][r] + b, 0.0f);
        }
    }
    transpose_frags(sw, acc0, lane, ah0, al0);
    transpose_frags(sw, acc1, lane, ah1, al1);

    // layer 2
    #pragma unroll
    for (int t = 0; t < 4; ++t) { acc0[t] = (f32x4){0.f,0.f,0.f,0.f}; acc1[t] = (f32x4){0.f,0.f,0.f,0.f}; }
    gemm64_dual(WF + 8192, lane, ah0, al0, ah1, al1, acc0, acc1);
    #pragma unroll
    for (int t = 0; t < 4; ++t) {
        float b = b2[t*16 + n];
        #pragma unroll
        for (int r = 0; r < 4; ++r) {
            acc0[t][r] = fmaxf(acc0[t][r] + b, 0.0f);
            acc1[t][r] = fmaxf(acc1[t][r] + b, 0.0f);
        }
    }
    transpose_frags(sw, acc0, lane, ah0, al0);   // a-frags = x2 (tile0)
    transpose_frags(sw, acc1, lane, ah1, al1);   // a-frags = x2 (tile1)

    // ---- heads + message + store, per tile (halves live accumulator regs) ----
    #pragma unroll
    for (int tile = 0; tile < 2; ++tile) {
        const int to = tile * 16;
        const bf16x8* ah = tile ? ah1 : ah0;
        const bf16x8* al = tile ? al1 : al0;

        f32x4 accS[4], accH[4];
        #pragma unroll
        for (int t = 0; t < 4; ++t) { accS[t] = (f32x4){0.f,0.f,0.f,0.f}; accH[t] = (f32x4){0.f,0.f,0.f,0.f}; }
        gemm64(WF + 2*8192, lane, ah, al, accS);
        gemm64(WF + 3*8192, lane, ah, al, accH);

        // message phase in D-layout registers: lane owns f=t*16+n, local edge e=to+mg*4+r
        {
            int sn[4];
            #pragma unroll
            for (int r = 0; r < 4; ++r) sn[r] = auxw[32 + to + mg*4 + r];
            #pragma unroll
            for (int t = 0; t < 4; ++t) {
                const int ff = t*16 + n;
                const float bBv = bB[ff];
                const float bCv = bC[ff];
                #pragma unroll
                for (int r = 0; r < 4; ++r) {
                    float vp = Vp[(size_t)sn[r]*DDIM + ff];
                    float sg = 1.0f / (1.0f + __expf(-(accS[t][r] + bBv)));
                    sw[(mg*4 + r)*PADS + ff] = fmaf(sg, vp, accH[t][r] + bCv);
                }
            }
        }
        __builtin_amdgcn_wave_barrier();

        // store each message row to its sorted position: 256B fully-coalesced rows
        #pragma unroll 4
        for (int r = 0; r < 16; ++r) {
            int p = auxw[to + r];
            M1s[(size_t)p*DDIM + lane] = sw[r*PADS + lane];
        }
        __builtin_amdgcn_wave_barrier();
    }
}

// E2: CSR reduce, one wave per node. Contiguous coalesced reads, no atomics,
// finalize fused (sqrt(relu((S2-S1)/deg)+eps)).
// cend = curs AFTER scatter: cend[n] = global end offset of node n's segment.
__global__ __launch_bounds__(256)
void e2_reduce_kernel(const float* __restrict__ M1s,
                      const int* __restrict__ cend, const int* __restrict__ degi,
                      float* __restrict__ out)
{
    const int nw = blockIdx.x * 4 + (threadIdx.x >> 6);  // node id
    if (nw >= NN) return;
    const int lane = threadIdx.x & 63;
    const int deg = degi[nw];
    const int start = cend[nw] - deg;
    const float* base = M1s + (size_t)start*DDIM + lane;
    float s1 = 0.f, s2 = 0.f;
    int i = 0;
    for (; i + 4 <= deg; i += 4) {
        float a = base[(size_t)(i+0)*DDIM];
        float b = base[(size_t)(i+1)*DDIM];
        float c = base[(size_t)(i+2)*DDIM];
        float d = base[(size_t)(i+3)*DDIM];
        s1 += a + b + c + d;
        s2 = fmaf(a, a, s2); s2 = fmaf(b, b, s2);
        s2 = fmaf(c, c, s2); s2 = fmaf(d, d, s2);
    }
    for (; i < deg; ++i) {
        float a = base[(size_t)i*DDIM];
        s1 += a;
        s2 = fmaf(a, a, s2);
    }
    float dn = deg > 1 ? (float)deg : 1.0f;
    float v = (s2 - s1) / dn;
    out[(size_t)nw*DDIM + lane] = sqrtf(fmaxf(v, 0.0f) + EPS_V);
}

extern "C" void kernel_launch(void* const* d_in, const int* in_sizes, int n_in,
                              void* d_out, int out_size, void* d_ws, size_t ws_size,
                              hipStream_t stream) {
    const float* V   = (const float*)d_in[0];
    const float* Eg  = (const float*)d_in[1];
    const int*   src = (const int*)d_in[2];
    const int*   dst = (const int*)d_in[3];
    const float* pAw = (const float*)d_in[4];
    const float* pAb = (const float*)d_in[5];
    const float* pBw = (const float*)d_in[6];
    const float* pBb = (const float*)d_in[7];
    const float* mW1 = (const float*)d_in[8];
    const float* mb1 = (const float*)d_in[9];
    const float* mW2 = (const float*)d_in[10];
    const float* mb2 = (const float*)d_in[11];
    const float* BW  = (const float*)d_in[12];
    const float* Bb  = (const float*)d_in[13];
    const float* CW  = (const float*)d_in[14];
    const float* Cb  = (const float*)d_in[15];
    float* out = (float*)d_out;

    float* ws    = (float*)d_ws;
    float* Vp    = ws;                                   // NN*DDIM f32 (3.2e6)
    int*   degi  = (int*)(ws + (size_t)NN*DDIM);         // NN i32
    int*   curs  = degi + NN;                            // NN i32
    int*   linc  = curs + NN;                            // NN i32
    int*   bsum  = linc + NN;                            // NB_SCAN i32
    int*   pinv  = bsum + NB_SCAN;                       // NE i32
    short* WF    = (short*)(pinv + NE);                  // 4*8192 shorts (64 KB)
    float* M1s   = (float*)(WF + 4*8192);                // NE*DDIM f32 (204.8 MB)

    hipMemsetAsync(degi, 0, (size_t)NN * sizeof(int), stream);

    prep_w_kernel<<<64, 256, 0, stream>>>(mW1, mW2, BW, CW, WF);
    node_pool_kernel<<<(NN + 63)/64, 256, 0, stream>>>(V, pAw, pAb, pBw, pBb, Vp, dst, degi);
    scan1_kernel<<<NB_SCAN, 256, 0, stream>>>(degi, linc, bsum);
    scan23_kernel<<<NB_SCAN, 256, 0, stream>>>(degi, linc, bsum, curs);
    scatter_kernel<<<(NE + 255)/256, 256, 0, stream>>>(dst, curs, pinv);
    e1_mlp_kernel<<<NE/128, 256, 0, stream>>>(Eg, src, pinv, WF,
                                              mb1, mb2, Bb, Cb, Vp, M1s);
    // after scatter, curs[n] = end offset of node n's CSR segment
    e2_reduce_kernel<<<(NN + 3)/4, 256, 0, stream>>>(M1s, curs, degi, out);
}

// Round 7
// 535.110 us; speedup vs baseline: 1.1183x; 1.1183x over previous
//
#include <hip/hip_runtime.h>

#define NN 50000
#define NE 800000
#define DDIM 64
#define PADX 68          // fp32 LDS row stride (node pool)
#define PADS 68          // fp32 per-wave scratch stride (rows are 272 B -> 16B aligned, odd*4 banks)
#define NB_SCAN ((NN + 255) / 256)   // 196
#define NEG_SLOPE 0.2f
#define EPS_V 1e-5f

typedef short bf16x8 __attribute__((ext_vector_type(8)));
typedef float f32x4 __attribute__((ext_vector_type(4)));

__device__ __forceinline__ float lrelu_f(float x) { return x >= 0.0f ? x : NEG_SLOPE * x; }

__device__ __forceinline__ unsigned short bf16_rn(float x) {
    union { float f; unsigned int u; } c; c.f = x;
    unsigned int r = c.u + 0x7FFF + ((c.u >> 16) & 1);
    return (unsigned short)(r >> 16);
}
__device__ __forceinline__ float bf16_tof(unsigned short h) {
    union { float f; unsigned int u; } c; c.u = ((unsigned int)h) << 16;
    return c.f;
}

// packed bf16 convert (RNE), 2 f32 -> u32 [lo=bf16(a) | hi=bf16(b)]
__device__ __forceinline__ unsigned cvtpk_bf16(float a, float b) {
    unsigned r;
    asm("v_cvt_pk_bf16_f32 %0, %1, %2" : "=v"(r) : "v"(a), "v"(b));
    return r;
}

// split 8 fp32 -> hi/lo bf16x8 (RNE both; ~2^-18 effective rel err) via v_cvt_pk_bf16_f32
__device__ __forceinline__ void split8(const float* __restrict__ v, bf16x8& h, bf16x8& l)
{
    union { bf16x8 v8; unsigned u[4]; } H, L;
    #pragma unroll
    for (int k = 0; k < 4; ++k) {
        float a = v[2*k], b = v[2*k+1];
        unsigned p = cvtpk_bf16(a, b);
        union { float f; unsigned u; } h0, h1;
        h0.u = p << 16;
        h1.u = p & 0xFFFF0000u;
        unsigned q = cvtpk_bf16(a - h0.f, b - h1.f);
        H.u[k] = p;
        L.u[k] = q;
    }
    h = H.v8; l = L.v8;
}

// ---------------- fp32 micro-tile GEMM helpers (node pooling only) ----------------
__device__ __forceinline__ void mma_tile(float acc[16], const float* __restrict__ XT,
                                         const float* __restrict__ Wc, int e0, int f0)
{
    #pragma unroll 4
    for (int kk = 0; kk < DDIM; kk += 4) {
        float4 A0 = *(const float4*)&XT[(kk+0)*PADX + e0];
        float4 A1 = *(const float4*)&XT[(kk+1)*PADX + e0];
        float4 A2 = *(const float4*)&XT[(kk+2)*PADX + e0];
        float4 A3 = *(const float4*)&XT[(kk+3)*PADX + e0];
        float4 B0 = *(const float4*)&Wc[(f0+0)*PADX + kk];
        float4 B1 = *(const float4*)&Wc[(f0+1)*PADX + kk];
        float4 B2 = *(const float4*)&Wc[(f0+2)*PADX + kk];
        float4 B3 = *(const float4*)&Wc[(f0+3)*PADX + kk];
        const float a[4][4] = {{A0.x,A0.y,A0.z,A0.w},{A1.x,A1.y,A1.z,A1.w},
                               {A2.x,A2.y,A2.z,A2.w},{A3.x,A3.y,A3.z,A3.w}};
        const float b[4][4] = {{B0.x,B0.y,B0.z,B0.w},{B1.x,B1.y,B1.z,B1.w},
                               {B2.x,B2.y,B2.z,B2.w},{B3.x,B3.y,B3.z,B3.w}};
        #pragma unroll
        for (int j = 0; j < 4; ++j)
            #pragma unroll
            for (int i = 0; i < 4; ++i)
                #pragma unroll
                for (int q = 0; q < 4; ++q)
                    acc[i*4+j] = fmaf(a[q][i], b[j][q], acc[i*4+j]);
    }
}

__device__ __forceinline__ void load_w_f32(float* __restrict__ Wc, const float* __restrict__ Wg, int tid)
{
    #pragma unroll
    for (int c = 0; c < 4; ++c) {
        int idx = (c << 10) + (tid << 2);
        int f = idx >> 6, k = idx & 63;
        *(float4*)&Wc[f*PADX + k] = *(const float4*)&Wg[idx];
    }
}

// ---------------- node pooling (fp32) + fused dst histogram ----------------
__global__ __launch_bounds__(256, 3)
void node_pool_kernel(const float* __restrict__ V,
                      const float* __restrict__ Aw, const float* __restrict__ Ab,
                      const float* __restrict__ Bw, const float* __restrict__ Bbv,
                      float* __restrict__ Vp,
                      const int* __restrict__ dst, int* __restrict__ degi)
{
    __shared__ float Wc[DDIM*PADX];
    __shared__ float XT[DDIM*PADX];
    const int tid = threadIdx.x;
    const int nb = blockIdx.x * 64;
    const int e0 = (tid & 15) << 2;
    const int f0 = (tid >> 4) << 2;

    #pragma unroll
    for (int c = 0; c < 4; ++c) {
        int idx = (c << 10) + (tid << 2);
        int e = idx >> 6, d = idx & 63;
        int row = nb + e; if (row > NN-1) row = NN-1;
        float4 v = *(const float4*)&V[(size_t)row*DDIM + d];
        XT[(d+0)*PADX + e] = lrelu_f(v.x);
        XT[(d+1)*PADX + e] = lrelu_f(v.y);
        XT[(d+2)*PADX + e] = lrelu_f(v.z);
        XT[(d+3)*PADX + e] = lrelu_f(v.w);
    }
    load_w_f32(Wc, Aw, tid);
    __syncthreads();

    float acc[16];
    #pragma unroll
    for (int i = 0; i < 16; ++i) acc[i] = 0.f;
    mma_tile(acc, XT, Wc, e0, f0);
    __syncthreads();

    {   // lrelu(acc + Ab) -> XT
        float4 bv = *(const float4*)&Ab[f0];
        const float ba[4] = {bv.x, bv.y, bv.z, bv.w};
        #pragma unroll
        for (int j = 0; j < 4; ++j) {
            float4 v;
            v.x = lrelu_f(acc[0*4+j] + ba[j]);
            v.y = lrelu_f(acc[1*4+j] + ba[j]);
            v.z = lrelu_f(acc[2*4+j] + ba[j]);
            v.w = lrelu_f(acc[3*4+j] + ba[j]);
            *(float4*)&XT[(f0+j)*PADX + e0] = v;
        }
    }
    load_w_f32(Wc, Bw, tid);
    __syncthreads();

    float acc2[16];
    #pragma unroll
    for (int i = 0; i < 16; ++i) acc2[i] = 0.f;
    mma_tile(acc2, XT, Wc, e0, f0);

    float4 bv = *(const float4*)&Bbv[f0];
    #pragma unroll
    for (int i = 0; i < 4; ++i) {
        int row = nb + e0 + i;
        if (row < NN) {
            float4 o;
            o.x = acc2[i*4+0] + bv.x;
            o.y = acc2[i*4+1] + bv.y;
            o.z = acc2[i*4+2] + bv.z;
            o.w = acc2[i*4+3] + bv.w;
            *(float4*)&Vp[(size_t)row*DDIM + f0] = o;
        }
    }

    // fused histogram tail: grid-stride over edges
    const int stride = gridDim.x * 256;
    for (int e = blockIdx.x * 256 + tid; e < NE; e += stride)
        atomicAdd(&degi[dst[e]], 1);
}

// ---------------- split-bf16 weight fragment precompute ----------------
// Layout: WF[L][t][ks][hl][lane][j] shorts; per-layer stride 8192 shorts.
// lane: n=lane&15 (feature col), kg=lane>>4; f=t*16+n; k=ks*32+kg*8+j.
__global__ __launch_bounds__(256)
void prep_w_kernel(const float* __restrict__ W1, const float* __restrict__ W2,
                   const float* __restrict__ WB, const float* __restrict__ WC,
                   short* __restrict__ WF)
{
    int gid = blockIdx.x * 256 + threadIdx.x;   // grid = 64 blocks -> 16384 threads
    int L = gid >> 12, r = gid & 4095;
    int t = r >> 10, ks = (r >> 9) & 1, lane = (r >> 3) & 63, j = r & 7;
    const float* Ws = (L == 0) ? W1 : (L == 1) ? W2 : (L == 2) ? WB : WC;
    int n = lane & 15, kg = lane >> 4;
    int f = t*16 + n, k = ks*32 + kg*8 + j;
    float v = Ws[f*64 + k];
    unsigned short h = bf16_rn(v);
    unsigned short l = bf16_rn(v - bf16_tof(h));
    int base = L*8192 + ((t*2 + ks)*2)*512 + lane*8 + j;
    WF[base]       = (short)h;
    WF[base + 512] = (short)l;
}

// ---------------- CSR build: scan / scatter ----------------
__global__ __launch_bounds__(256)
void scan1_kernel(const int* __restrict__ degi, int* __restrict__ linc, int* __restrict__ bsum)
{
    __shared__ int ws[4];
    const int tid = threadIdx.x;
    const int lane = tid & 63, wv = tid >> 6;
    int i = blockIdx.x * 256 + tid;
    int v = (i < NN) ? degi[i] : 0;
    int sc = v;
    #pragma unroll
    for (int off = 1; off < 64; off <<= 1) {
        int t = __shfl_up(sc, off, 64);
        if (lane >= off) sc += t;
    }
    if (lane == 63) ws[wv] = sc;
    __syncthreads();
    int wb = 0;
    #pragma unroll
    for (int w = 0; w < 4; ++w) if (w < wv) wb += ws[w];
    int incl = sc + wb;
    if (i < NN) linc[i] = incl;
    if (tid == 255) bsum[blockIdx.x] = incl;
}

__global__ __launch_bounds__(256)
void scan23_kernel(const int* __restrict__ degi, const int* __restrict__ linc,
                   const int* __restrict__ bsum, int* __restrict__ curs)
{
    __shared__ int ws[4];
    __shared__ int base_s;
    const int tid = threadIdx.x;
    const int lane = tid & 63, wv = tid >> 6;
    int v = (tid < NB_SCAN) ? bsum[tid] : 0;
    int sc = v;
    #pragma unroll
    for (int off = 1; off < 64; off <<= 1) {
        int t = __shfl_up(sc, off, 64);
        if (lane >= off) sc += t;
    }
    if (lane == 63) ws[wv] = sc;
    __syncthreads();
    int wb = 0;
    #pragma unroll
    for (int w = 0; w < 4; ++w) if (w < wv) wb += ws[w];
    if (tid == blockIdx.x) base_s = sc + wb - v;
    __syncthreads();
    int i = blockIdx.x * 256 + tid;
    if (i < NN) curs[i] = base_s + linc[i] - degi[i];
}

// scatter: compute inverse permutation pinv[e] = sorted position of edge e.
// After this kernel, curs[n] = global END offset of node n's segment.
__global__ __launch_bounds__(256)
void scatter_kernel(const int* __restrict__ dst, int* __restrict__ cursor, int* __restrict__ pinv)
{
    int e = blockIdx.x * 256 + threadIdx.x;
    if (e < NE) {
        pinv[e] = atomicAdd(&cursor[dst[e]], 1);
    }
}

// ---------------- natural-order split-bf16 MFMA edge MLP + message ----------------
// Dual-tile GEMM with B-fragments in LDS (bw): loaded once per block per layer,
// read via ds_read_b128 instead of per-wave L2 traffic (6x L2 cut).
__device__ __forceinline__ void gemm64_dual_lds(const short* bw, int lane,
                                                const bf16x8 ah0[2], const bf16x8 al0[2],
                                                const bf16x8 ah1[2], const bf16x8 al1[2],
                                                f32x4 acc0[4], f32x4 acc1[4])
{
    #pragma unroll
    for (int ks = 0; ks < 2; ++ks) {
        bf16x8 bh[4], bl[4];
        #pragma unroll
        for (int t = 0; t < 4; ++t) {
            bh[t] = *(const bf16x8*)&bw[(((t*2 + ks)*2 + 0)*64 + lane)*8];
            bl[t] = *(const bf16x8*)&bw[(((t*2 + ks)*2 + 1)*64 + lane)*8];
        }
        #pragma unroll
        for (int t = 0; t < 4; ++t) {
            acc0[t] = __builtin_amdgcn_mfma_f32_16x16x32_bf16(al0[ks], bh[t], acc0[t], 0, 0, 0);
            acc1[t] = __builtin_amdgcn_mfma_f32_16x16x32_bf16(al1[ks], bh[t], acc1[t], 0, 0, 0);
            acc0[t] = __builtin_amdgcn_mfma_f32_16x16x32_bf16(ah0[ks], bl[t], acc0[t], 0, 0, 0);
            acc1[t] = __builtin_amdgcn_mfma_f32_16x16x32_bf16(ah1[ks], bl[t], acc1[t], 0, 0, 0);
            acc0[t] = __builtin_amdgcn_mfma_f32_16x16x32_bf16(ah0[ks], bh[t], acc0[t], 0, 0, 0);
            acc1[t] = __builtin_amdgcn_mfma_f32_16x16x32_bf16(ah1[ks], bh[t], acc1[t], 0, 0, 0);
        }
    }
}

// Single-tile transpose through a 16-row per-wave LDS tile (reused sequentially;
// per-wave LDS ops are in-order, wave_barrier fences compiler reordering).
__device__ __forceinline__ void transpose_frags(float* __restrict__ sw, const f32x4 y[4],
                                                int lane, bf16x8 ah[2], bf16x8 al[2])
{
    const int n = lane & 15, mg = lane >> 4;
    #pragma unroll
    for (int t = 0; t < 4; ++t)
        #pragma unroll
        for (int r = 0; r < 4; ++r)
            sw[(mg*4 + r)*PADS + t*16 + n] = y[t][r];
    __builtin_amdgcn_wave_barrier();
    const int m = lane & 15, kg = lane >> 4;   // m: edge row, kg: k-group
    float x[16];
    *(float4*)&x[0]  = *(const float4*)&sw[m*PADS + kg*8];
    *(float4*)&x[4]  = *(const float4*)&sw[m*PADS + kg*8 + 4];
    *(float4*)&x[8]  = *(const float4*)&sw[m*PADS + 32 + kg*8];
    *(float4*)&x[12] = *(const float4*)&sw[m*PADS + 32 + kg*8 + 4];
    split8(&x[0], ah[0], al[0]);
    split8(&x[8], ah[1], al[1]);
    __builtin_amdgcn_wave_barrier();
}

// E1: natural edge order. Coalesced E reads, MLP+heads+message, write message row
// to its dst-sorted position pinv[e]. No atomics, no eidx gather.
// B-fragments staged in LDS per layer (16 KB), block-cooperative.
__global__ __launch_bounds__(256, 3)
void e1_mlp_kernel(const float* __restrict__ Eg,
                   const int* __restrict__ src, const int* __restrict__ pinv,
                   const short* __restrict__ WF,
                   const float* __restrict__ b1, const float* __restrict__ b2,
                   const float* __restrict__ bB, const float* __restrict__ bC,
                   const float* __restrict__ Vp,
                   float* __restrict__ M1s)
{
    __shared__ short bw[8192];                 // current layer's B fragments (16384 B)
    __shared__ float scratch[4 * 16 * PADS];   // per-wave 16x68 fp32 tile (17408 B)
    __shared__ int aux[4 * 64];                // per-wave: [0..31]=pinv, [32..63]=src

    const int tid = threadIdx.x;
    const int lane = tid & 63, wv = tid >> 6;
    float* sw = scratch + wv * 16 * PADS;
    int* auxw = aux + wv * 64;

    const int e0 = blockIdx.x * 128 + wv * 32;  // this wave's 32 edges (natural order)
    const int m = lane & 15, kg = lane >> 4;
    const int n = lane & 15, mg = lane >> 4;

    // cooperative layer-weight stage: 16 KB, 1024 uint4 across 256 threads
    auto load_layer = [&](const short* Wg) {
        __syncthreads();                        // all waves done with previous layer's bw
        const uint4* s = (const uint4*)Wg;
        uint4* d = (uint4*)bw;
        #pragma unroll
        for (int c = 0; c < 4; ++c)
            d[c*256 + tid] = s[c*256 + tid];
        __syncthreads();
    };

    if (lane < 32) {
        auxw[lane]      = pinv[e0 + lane];
        auxw[32 + lane] = src[e0 + lane];
    }
    // A-fragments straight from CONSECUTIVE E rows (streaming, no gather)
    bf16x8 ah0[2], al0[2], ah1[2], al1[2];
    {
        const float* er0 = Eg + (size_t)(e0 + m)*DDIM + kg*8;
        const float* er1 = Eg + (size_t)(e0 + 16 + m)*DDIM + kg*8;
        float x[16];
        *(float4*)&x[0]  = *(const float4*)&er0[0];
        *(float4*)&x[4]  = *(const float4*)&er0[4];
        *(float4*)&x[8]  = *(const float4*)&er0[32];
        *(float4*)&x[12] = *(const float4*)&er0[36];
        split8(&x[0], ah0[0], al0[0]);
        split8(&x[8], ah0[1], al0[1]);
        *(float4*)&x[0]  = *(const float4*)&er1[0];
        *(float4*)&x[4]  = *(const float4*)&er1[4];
        *(float4*)&x[8]  = *(const float4*)&er1[32];
        *(float4*)&x[12] = *(const float4*)&er1[36];
        split8(&x[0], ah1[0], al1[0]);
        split8(&x[8], ah1[1], al1[1]);
    }

    // layer 1
    load_layer(WF);
    f32x4 acc0[4], acc1[4];
    #pragma unroll
    for (int t = 0; t < 4; ++t) { acc0[t] = (f32x4){0.f,0.f,0.f,0.f}; acc1[t] = (f32x4){0.f,0.f,0.f,0.f}; }
    gemm64_dual_lds(bw, lane, ah0, al0, ah1, al1, acc0, acc1);
    #pragma unroll
    for (int t = 0; t < 4; ++t) {
        float b = b1[t*16 + n];
        #pragma unroll
        for (int r = 0; r < 4; ++r) {
            acc0[t][r] = fmaxf(acc0[t][r] + b, 0.0f);
            acc1[t][r] = fmaxf(acc1[t][r] + b, 0.0f);
        }
    }
    transpose_frags(sw, acc0, lane, ah0, al0);
    transpose_frags(sw, acc1, lane, ah1, al1);

    // layer 2
    load_layer(WF + 8192);
    #pragma unroll
    for (int t = 0; t < 4; ++t) { acc0[t] = (f32x4){0.f,0.f,0.f,0.f}; acc1[t] = (f32x4){0.f,0.f,0.f,0.f}; }
    gemm64_dual_lds(bw, lane, ah0, al0, ah1, al1, acc0, acc1);
    #pragma unroll
    for (int t = 0; t < 4; ++t) {
        float b = b2[t*16 + n];
        #pragma unroll
        for (int r = 0; r < 4; ++r) {
            acc0[t][r] = fmaxf(acc0[t][r] + b, 0.0f);
            acc1[t][r] = fmaxf(acc1[t][r] + b, 0.0f);
        }
    }
    transpose_frags(sw, acc0, lane, ah0, al0);   // a-frags = x2 (tile0)
    transpose_frags(sw, acc1, lane, ah1, al1);   // a-frags = x2 (tile1)

    // scale head (both tiles)
    f32x4 accS0[4], accS1[4];
    load_layer(WF + 2*8192);
    #pragma unroll
    for (int t = 0; t < 4; ++t) { accS0[t] = (f32x4){0.f,0.f,0.f,0.f}; accS1[t] = (f32x4){0.f,0.f,0.f,0.f}; }
    gemm64_dual_lds(bw, lane, ah0, al0, ah1, al1, accS0, accS1);

    // shift head (both tiles)
    f32x4 accH0[4], accH1[4];
    load_layer(WF + 3*8192);
    #pragma unroll
    for (int t = 0; t < 4; ++t) { accH0[t] = (f32x4){0.f,0.f,0.f,0.f}; accH1[t] = (f32x4){0.f,0.f,0.f,0.f}; }
    gemm64_dual_lds(bw, lane, ah0, al0, ah1, al1, accH0, accH1);

    // ---- message + store per tile (16-row scratch reused) ----
    #pragma unroll
    for (int tile = 0; tile < 2; ++tile) {
        const int to = tile * 16;
        f32x4* accS = tile ? accS1 : accS0;
        f32x4* accH = tile ? accH1 : accH0;

        {
            int sn[4];
            #pragma unroll
            for (int r = 0; r < 4; ++r) sn[r] = auxw[32 + to + mg*4 + r];
            #pragma unroll
            for (int t = 0; t < 4; ++t) {
                const int ff = t*16 + n;
                const float bBv = bB[ff];
                const float bCv = bC[ff];
                #pragma unroll
                for (int r = 0; r < 4; ++r) {
                    float vp = Vp[(size_t)sn[r]*DDIM + ff];
                    float sg = 1.0f / (1.0f + __expf(-(accS[t][r] + bBv)));
                    sw[(mg*4 + r)*PADS + ff] = fmaf(sg, vp, accH[t][r] + bCv);
                }
            }
        }
        __builtin_amdgcn_wave_barrier();

        // store each message row to its sorted position: 256B fully-coalesced rows
        #pragma unroll 4
        for (int r = 0; r < 16; ++r) {
            int p = auxw[to + r];
            M1s[(size_t)p*DDIM + lane] = sw[r*PADS + lane];
        }
        __builtin_amdgcn_wave_barrier();
    }
}

// E2: CSR reduce, one wave per node. Contiguous coalesced reads, no atomics,
// finalize fused (sqrt(relu((S2-S1)/deg)+eps)).
// cend = curs AFTER scatter: cend[n] = global end offset of node n's segment.
__global__ __launch_bounds__(256)
void e2_reduce_kernel(const float* __restrict__ M1s,
                      const int* __restrict__ cend, const int* __restrict__ degi,
                      float* __restrict__ out)
{
    const int nw = blockIdx.x * 4 + (threadIdx.x >> 6);  // node id
    if (nw >= NN) return;
    const int lane = threadIdx.x & 63;
    const int deg = degi[nw];
    const int start = cend[nw] - deg;
    const float* base = M1s + (size_t)start*DDIM + lane;
    float s1 = 0.f, s2 = 0.f;
    int i = 0;
    for (; i + 4 <= deg; i += 4) {
        float a = base[(size_t)(i+0)*DDIM];
        float b = base[(size_t)(i+1)*DDIM];
        float c = base[(size_t)(i+2)*DDIM];
        float d = base[(size_t)(i+3)*DDIM];
        s1 += a + b + c + d;
        s2 = fmaf(a, a, s2); s2 = fmaf(b, b, s2);
        s2 = fmaf(c, c, s2); s2 = fmaf(d, d, s2);
    }
    for (; i < deg; ++i) {
        float a = base[(size_t)i*DDIM];
        s1 += a;
        s2 = fmaf(a, a, s2);
    }
    float dn = deg > 1 ? (float)deg : 1.0f;
    float v = (s2 - s1) / dn;
    out[(size_t)nw*DDIM + lane] = sqrtf(fmaxf(v, 0.0f) + EPS_V);
}

extern "C" void kernel_launch(void* const* d_in, const int* in_sizes, int n_in,
                              void* d_out, int out_size, void* d_ws, size_t ws_size,
                              hipStream_t stream) {
    const float* V   = (const float*)d_in[0];
    const float* Eg  = (const float*)d_in[1];
    const int*   src = (const int*)d_in[2];
    const int*   dst = (const int*)d_in[3];
    const float* pAw = (const float*)d_in[4];
    const float* pAb = (const float*)d_in[5];
    const float* pBw = (const float*)d_in[6];
    const float* pBb = (const float*)d_in[7];
    const float* mW1 = (const float*)d_in[8];
    const float* mb1 = (const float*)d_in[9];
    const float* mW2 = (const float*)d_in[10];
    const float* mb2 = (const float*)d_in[11];
    const float* BW  = (const float*)d_in[12];
    const float* Bb  = (const float*)d_in[13];
    const float* CW  = (const float*)d_in[14];
    const float* Cb  = (const float*)d_in[15];
    float* out = (float*)d_out;

    float* ws    = (float*)d_ws;
    float* Vp    = ws;                                   // NN*DDIM f32 (3.2e6)
    int*   degi  = (int*)(ws + (size_t)NN*DDIM);         // NN i32
    int*   curs  = degi + NN;                            // NN i32
    int*   linc  = curs + NN;                            // NN i32
    int*   bsum  = linc + NN;                            // NB_SCAN i32
    int*   pinv  = bsum + NB_SCAN;                       // NE i32
    short* WF    = (short*)(pinv + NE);                  // 4*8192 shorts (64 KB)
    float* M1s   = (float*)(WF + 4*8192);                // NE*DDIM f32 (204.8 MB)

    hipMemsetAsync(degi, 0, (size_t)NN * sizeof(int), stream);

    prep_w_kernel<<<64, 256, 0, stream>>>(mW1, mW2, BW, CW, WF);
    node_pool_kernel<<<(NN + 63)/64, 256, 0, stream>>>(V, pAw, pAb, pBw, pBb, Vp, dst, degi);
    scan1_kernel<<<NB_SCAN, 256, 0, stream>>>(degi, linc, bsum);
    scan23_kernel<<<NB_SCAN, 256, 0, stream>>>(degi, linc, bsum, curs);
    scatter_kernel<<<(NE + 255)/256, 256, 0, stream>>>(dst, curs, pinv);
    e1_mlp_kernel<<<NE/128, 256, 0, stream>>>(Eg, src, pinv, WF,
                                              mb1, mb2, Bb, Cb, Vp, M1s);
    // after scatter, curs[n] = end offset of node n's CSR segment
    e2_reduce_kernel<<<(NN + 3)/4, 256, 0, stream>>>(M1s, curs, degi, out);
}

// Round 8
// 505.828 us; speedup vs baseline: 1.1830x; 1.0579x over previous
//
#include <hip/hip_runtime.h>

#define NN 50000
#define NE 800000
#define DDIM 64
#define PADX 68          // fp32 LDS row stride (node pool)
#define PADS 68          // fp32 per-wave scratch stride (rows are 272 B -> 16B aligned, odd*4 banks)
#define NB_SCAN ((NN + 255) / 256)   // 196
#define NEG_SLOPE 0.2f
#define EPS_V 1e-5f

typedef short bf16x8 __attribute__((ext_vector_type(8)));
typedef float f32x4 __attribute__((ext_vector_type(4)));

__device__ __forceinline__ float lrelu_f(float x) { return x >= 0.0f ? x : NEG_SLOPE * x; }

__device__ __forceinline__ unsigned short bf16_rn(float x) {
    union { float f; unsigned int u; } c; c.f = x;
    unsigned int r = c.u + 0x7FFF + ((c.u >> 16) & 1);
    return (unsigned short)(r >> 16);
}
__device__ __forceinline__ float bf16_tof(unsigned short h) {
    union { float f; unsigned int u; } c; c.u = ((unsigned int)h) << 16;
    return c.f;
}

// packed bf16 convert (RNE), 2 f32 -> u32 [lo=bf16(a) | hi=bf16(b)]
__device__ __forceinline__ unsigned cvtpk_bf16(float a, float b) {
    unsigned r;
    asm("v_cvt_pk_bf16_f32 %0, %1, %2" : "=v"(r) : "v"(a), "v"(b));
    return r;
}

// split 8 fp32 -> hi/lo bf16x8 (RNE both; ~2^-18 effective rel err) via v_cvt_pk_bf16_f32
__device__ __forceinline__ void split8(const float* __restrict__ v, bf16x8& h, bf16x8& l)
{
    union { bf16x8 v8; unsigned u[4]; } H, L;
    #pragma unroll
    for (int k = 0; k < 4; ++k) {
        float a = v[2*k], b = v[2*k+1];
        unsigned p = cvtpk_bf16(a, b);
        union { float f; unsigned u; } h0, h1;
        h0.u = p << 16;
        h1.u = p & 0xFFFF0000u;
        unsigned q = cvtpk_bf16(a - h0.f, b - h1.f);
        H.u[k] = p;
        L.u[k] = q;
    }
    h = H.v8; l = L.v8;
}

// ---------------- fp32 micro-tile GEMM helpers (node pooling only) ----------------
__device__ __forceinline__ void mma_tile(float acc[16], const float* __restrict__ XT,
                                         const float* __restrict__ Wc, int e0, int f0)
{
    #pragma unroll 4
    for (int kk = 0; kk < DDIM; kk += 4) {
        float4 A0 = *(const float4*)&XT[(kk+0)*PADX + e0];
        float4 A1 = *(const float4*)&XT[(kk+1)*PADX + e0];
        float4 A2 = *(const float4*)&XT[(kk+2)*PADX + e0];
        float4 A3 = *(const float4*)&XT[(kk+3)*PADX + e0];
        float4 B0 = *(const float4*)&Wc[(f0+0)*PADX + kk];
        float4 B1 = *(const float4*)&Wc[(f0+1)*PADX + kk];
        float4 B2 = *(const float4*)&Wc[(f0+2)*PADX + kk];
        float4 B3 = *(const float4*)&Wc[(f0+3)*PADX + kk];
        const float a[4][4] = {{A0.x,A0.y,A0.z,A0.w},{A1.x,A1.y,A1.z,A1.w},
                               {A2.x,A2.y,A2.z,A2.w},{A3.x,A3.y,A3.z,A3.w}};
        const float b[4][4] = {{B0.x,B0.y,B0.z,B0.w},{B1.x,B1.y,B1.z,B1.w},
                               {B2.x,B2.y,B2.z,B2.w},{B3.x,B3.y,B3.z,B3.w}};
        #pragma unroll
        for (int j = 0; j < 4; ++j)
            #pragma unroll
            for (int i = 0; i < 4; ++i)
                #pragma unroll
                for (int q = 0; q < 4; ++q)
                    acc[i*4+j] = fmaf(a[q][i], b[j][q], acc[i*4+j]);
    }
}

__device__ __forceinline__ void load_w_f32(float* __restrict__ Wc, const float* __restrict__ Wg, int tid)
{
    #pragma unroll
    for (int c = 0; c < 4; ++c) {
        int idx = (c << 10) + (tid << 2);
        int f = idx >> 6, k = idx & 63;
        *(float4*)&Wc[f*PADX + k] = *(const float4*)&Wg[idx];
    }
}

// ---------------- node pooling (fp32) + fused dst histogram ----------------
__global__ __launch_bounds__(256, 3)
void node_pool_kernel(const float* __restrict__ V,
                      const float* __restrict__ Aw, const float* __restrict__ Ab,
                      const float* __restrict__ Bw, const float* __restrict__ Bbv,
                      float* __restrict__ Vp,
                      const int* __restrict__ dst, int* __restrict__ degi)
{
    __shared__ float Wc[DDIM*PADX];
    __shared__ float XT[DDIM*PADX];
    const int tid = threadIdx.x;
    const int nb = blockIdx.x * 64;
    const int e0 = (tid & 15) << 2;
    const int f0 = (tid >> 4) << 2;

    #pragma unroll
    for (int c = 0; c < 4; ++c) {
        int idx = (c << 10) + (tid << 2);
        int e = idx >> 6, d = idx & 63;
        int row = nb + e; if (row > NN-1) row = NN-1;
        float4 v = *(const float4*)&V[(size_t)row*DDIM + d];
        XT[(d+0)*PADX + e] = lrelu_f(v.x);
        XT[(d+1)*PADX + e] = lrelu_f(v.y);
        XT[(d+2)*PADX + e] = lrelu_f(v.z);
        XT[(d+3)*PADX + e] = lrelu_f(v.w);
    }
    load_w_f32(Wc, Aw, tid);
    __syncthreads();

    float acc[16];
    #pragma unroll
    for (int i = 0; i < 16; ++i) acc[i] = 0.f;
    mma_tile(acc, XT, Wc, e0, f0);
    __syncthreads();

    {   // lrelu(acc + Ab) -> XT
        float4 bv = *(const float4*)&Ab[f0];
        const float ba[4] = {bv.x, bv.y, bv.z, bv.w};
        #pragma unroll
        for (int j = 0; j < 4; ++j) {
            float4 v;
            v.x = lrelu_f(acc[0*4+j] + ba[j]);
            v.y = lrelu_f(acc[1*4+j] + ba[j]);
            v.z = lrelu_f(acc[2*4+j] + ba[j]);
            v.w = lrelu_f(acc[3*4+j] + ba[j]);
            *(float4*)&XT[(f0+j)*PADX + e0] = v;
        }
    }
    load_w_f32(Wc, Bw, tid);
    __syncthreads();

    float acc2[16];
    #pragma unroll
    for (int i = 0; i < 16; ++i) acc2[i] = 0.f;
    mma_tile(acc2, XT, Wc, e0, f0);

    float4 bv = *(const float4*)&Bbv[f0];
    #pragma unroll
    for (int i = 0; i < 4; ++i) {
        int row = nb + e0 + i;
        if (row < NN) {
            float4 o;
            o.x = acc2[i*4+0] + bv.x;
            o.y = acc2[i*4+1] + bv.y;
            o.z = acc2[i*4+2] + bv.z;
            o.w = acc2[i*4+3] + bv.w;
            *(float4*)&Vp[(size_t)row*DDIM + f0] = o;
        }
    }

    // fused histogram tail: grid-stride over edges
    const int stride = gridDim.x * 256;
    for (int e = blockIdx.x * 256 + tid; e < NE; e += stride)
        atomicAdd(&degi[dst[e]], 1);
}

// ---------------- split-bf16 weight fragment precompute ----------------
// Layout: WF[L][t][ks][hl][lane][j] shorts; per-layer stride 8192 shorts.
// lane: n=lane&15 (feature col), kg=lane>>4; f=t*16+n; k=ks*32+kg*8+j.
__global__ __launch_bounds__(256)
void prep_w_kernel(const float* __restrict__ W1, const float* __restrict__ W2,
                   const float* __restrict__ WB, const float* __restrict__ WC,
                   short* __restrict__ WF)
{
    int gid = blockIdx.x * 256 + threadIdx.x;   // grid = 64 blocks -> 16384 threads
    int L = gid >> 12, r = gid & 4095;
    int t = r >> 10, ks = (r >> 9) & 1, lane = (r >> 3) & 63, j = r & 7;
    const float* Ws = (L == 0) ? W1 : (L == 1) ? W2 : (L == 2) ? WB : WC;
    int n = lane & 15, kg = lane >> 4;
    int f = t*16 + n, k = ks*32 + kg*8 + j;
    float v = Ws[f*64 + k];
    unsigned short h = bf16_rn(v);
    unsigned short l = bf16_rn(v - bf16_tof(h));
    int base = L*8192 + ((t*2 + ks)*2)*512 + lane*8 + j;
    WF[base]       = (short)h;
    WF[base + 512] = (short)l;
}

// ---------------- CSR build: scan / scatter ----------------
__global__ __launch_bounds__(256)
void scan1_kernel(const int* __restrict__ degi, int* __restrict__ linc, int* __restrict__ bsum)
{
    __shared__ int ws[4];
    const int tid = threadIdx.x;
    const int lane = tid & 63, wv = tid >> 6;
    int i = blockIdx.x * 256 + tid;
    int v = (i < NN) ? degi[i] : 0;
    int sc = v;
    #pragma unroll
    for (int off = 1; off < 64; off <<= 1) {
        int t = __shfl_up(sc, off, 64);
        if (lane >= off) sc += t;
    }
    if (lane == 63) ws[wv] = sc;
    __syncthreads();
    int wb = 0;
    #pragma unroll
    for (int w = 0; w < 4; ++w) if (w < wv) wb += ws[w];
    int incl = sc + wb;
    if (i < NN) linc[i] = incl;
    if (tid == 255) bsum[blockIdx.x] = incl;
}

__global__ __launch_bounds__(256)
void scan23_kernel(const int* __restrict__ degi, const int* __restrict__ linc,
                   const int* __restrict__ bsum, int* __restrict__ curs)
{
    __shared__ int ws[4];
    __shared__ int base_s;
    const int tid = threadIdx.x;
    const int lane = tid & 63, wv = tid >> 6;
    int v = (tid < NB_SCAN) ? bsum[tid] : 0;
    int sc = v;
    #pragma unroll
    for (int off = 1; off < 64; off <<= 1) {
        int t = __shfl_up(sc, off, 64);
        if (lane >= off) sc += t;
    }
    if (lane == 63) ws[wv] = sc;
    __syncthreads();
    int wb = 0;
    #pragma unroll
    for (int w = 0; w < 4; ++w) if (w < wv) wb += ws[w];
    if (tid == blockIdx.x) base_s = sc + wb - v;
    __syncthreads();
    int i = blockIdx.x * 256 + tid;
    if (i < NN) curs[i] = base_s + linc[i] - degi[i];
}

// scatter: build dst-sorted edge list eidx
__global__ __launch_bounds__(256)
void scatter_kernel(const int* __restrict__ dst, int* __restrict__ cursor, int* __restrict__ eidx)
{
    int e = blockIdx.x * 256 + threadIdx.x;
    if (e < NE) {
        int p = atomicAdd(&cursor[dst[e]], 1);
        eidx[p] = e;
    }
}

// ---------------- fused dst-sorted split-bf16 MFMA edge kernel ----------------
// Dual-tile GEMM with B-fragments in LDS (bw): loaded once per block per layer,
// read via ds_read_b128 instead of per-wave L2 traffic (6x L2 cut).
__device__ __forceinline__ void gemm64_dual_lds(const short* bw, int lane,
                                                const bf16x8 ah0[2], const bf16x8 al0[2],
                                                const bf16x8 ah1[2], const bf16x8 al1[2],
                                                f32x4 acc0[4], f32x4 acc1[4])
{
    #pragma unroll
    for (int ks = 0; ks < 2; ++ks) {
        bf16x8 bh[4], bl[4];
        #pragma unroll
        for (int t = 0; t < 4; ++t) {
            bh[t] = *(const bf16x8*)&bw[(((t*2 + ks)*2 + 0)*64 + lane)*8];
            bl[t] = *(const bf16x8*)&bw[(((t*2 + ks)*2 + 1)*64 + lane)*8];
        }
        #pragma unroll
        for (int t = 0; t < 4; ++t) {
            acc0[t] = __builtin_amdgcn_mfma_f32_16x16x32_bf16(al0[ks], bh[t], acc0[t], 0, 0, 0);
            acc1[t] = __builtin_amdgcn_mfma_f32_16x16x32_bf16(al1[ks], bh[t], acc1[t], 0, 0, 0);
            acc0[t] = __builtin_amdgcn_mfma_f32_16x16x32_bf16(ah0[ks], bl[t], acc0[t], 0, 0, 0);
            acc1[t] = __builtin_amdgcn_mfma_f32_16x16x32_bf16(ah1[ks], bl[t], acc1[t], 0, 0, 0);
            acc0[t] = __builtin_amdgcn_mfma_f32_16x16x32_bf16(ah0[ks], bh[t], acc0[t], 0, 0, 0);
            acc1[t] = __builtin_amdgcn_mfma_f32_16x16x32_bf16(ah1[ks], bh[t], acc1[t], 0, 0, 0);
        }
    }
}

// Single-tile transpose through a 16-row per-wave LDS tile (reused sequentially;
// per-wave LDS ops are in-order, wave_barrier fences compiler reordering).
__device__ __forceinline__ void transpose_frags(float* __restrict__ sw, const f32x4 y[4],
                                                int lane, bf16x8 ah[2], bf16x8 al[2])
{
    const int n = lane & 15, mg = lane >> 4;
    #pragma unroll
    for (int t = 0; t < 4; ++t)
        #pragma unroll
        for (int r = 0; r < 4; ++r)
            sw[(mg*4 + r)*PADS + t*16 + n] = y[t][r];
    __builtin_amdgcn_wave_barrier();
    const int m = lane & 15, kg = lane >> 4;   // m: edge row, kg: k-group
    float x[16];
    *(float4*)&x[0]  = *(const float4*)&sw[m*PADS + kg*8];
    *(float4*)&x[4]  = *(const float4*)&sw[m*PADS + kg*8 + 4];
    *(float4*)&x[8]  = *(const float4*)&sw[m*PADS + 32 + kg*8];
    *(float4*)&x[12] = *(const float4*)&sw[m*PADS + 32 + kg*8 + 4];
    split8(&x[0], ah[0], al[0]);
    split8(&x[8], ah[1], al[1]);
    __builtin_amdgcn_wave_barrier();
}

// Fused edge kernel: dst-sorted eidx gather -> MLP (bw in LDS) -> heads -> message
// -> per-wave segmented reduce with carry -> atomicAdd only at segment closes.
// Two-pass message/reduce over a 16-row scratch keeps LDS at 4 blocks/CU.
__global__ __launch_bounds__(256, 3)
void edge_fused_kernel(const float* __restrict__ Eg,
                       const int* __restrict__ src, const int* __restrict__ dst,
                       const int* __restrict__ eidx,
                       const short* __restrict__ WF,
                       const float* __restrict__ b1, const float* __restrict__ b2,
                       const float* __restrict__ bB, const float* __restrict__ bC,
                       const float* __restrict__ Vp,
                       float* __restrict__ S1, float* __restrict__ S2)
{
    __shared__ short bw[8192];                 // current layer's B fragments (16384 B)
    __shared__ float scratch[4 * 16 * PADS];   // per-wave 16x68 fp32 tile (17408 B)
    __shared__ int aux[4 * 64];                // per-wave: [0..31]=src, [32..63]=dst

    const int tid = threadIdx.x;
    const int lane = tid & 63, wv = tid >> 6;
    float* sw = scratch + wv * 16 * PADS;
    int* auxw = aux + wv * 64;

    const int ew = blockIdx.x * 128 + wv * 32;  // this wave's 32 edges (dst-sorted)
    const int m = lane & 15, kg = lane >> 4;
    const int n = lane & 15, mg = lane >> 4;

    // cooperative layer-weight stage: 16 KB, 1024 uint4 across 256 threads
    auto load_layer = [&](const short* Wg) {
        __syncthreads();                        // all waves done with previous layer's bw
        const uint4* s = (const uint4*)Wg;
        uint4* d = (uint4*)bw;
        #pragma unroll
        for (int c = 0; c < 4; ++c)
            d[c*256 + tid] = s[c*256 + tid];
        __syncthreads();
    };

    if (lane < 32) {
        int eg = eidx[ew + lane];
        auxw[lane]      = src[eg];
        auxw[32 + lane] = dst[eg];
    }
    // A-fragments from gathered E rows (256B-row gather, 4 full lines each)
    bf16x8 ah0[2], al0[2], ah1[2], al1[2];
    {
        int eg0 = eidx[ew + m];
        int eg1 = eidx[ew + 16 + m];
        const float* er0 = Eg + (size_t)eg0*DDIM + kg*8;
        const float* er1 = Eg + (size_t)eg1*DDIM + kg*8;
        float x[16];
        *(float4*)&x[0]  = *(const float4*)&er0[0];
        *(float4*)&x[4]  = *(const float4*)&er0[4];
        *(float4*)&x[8]  = *(const float4*)&er0[32];
        *(float4*)&x[12] = *(const float4*)&er0[36];
        split8(&x[0], ah0[0], al0[0]);
        split8(&x[8], ah0[1], al0[1]);
        *(float4*)&x[0]  = *(const float4*)&er1[0];
        *(float4*)&x[4]  = *(const float4*)&er1[4];
        *(float4*)&x[8]  = *(const float4*)&er1[32];
        *(float4*)&x[12] = *(const float4*)&er1[36];
        split8(&x[0], ah1[0], al1[0]);
        split8(&x[8], ah1[1], al1[1]);
    }

    // layer 1
    load_layer(WF);
    f32x4 acc0[4], acc1[4];
    #pragma unroll
    for (int t = 0; t < 4; ++t) { acc0[t] = (f32x4){0.f,0.f,0.f,0.f}; acc1[t] = (f32x4){0.f,0.f,0.f,0.f}; }
    gemm64_dual_lds(bw, lane, ah0, al0, ah1, al1, acc0, acc1);
    #pragma unroll
    for (int t = 0; t < 4; ++t) {
        float b = b1[t*16 + n];
        #pragma unroll
        for (int r = 0; r < 4; ++r) {
            acc0[t][r] = fmaxf(acc0[t][r] + b, 0.0f);
            acc1[t][r] = fmaxf(acc1[t][r] + b, 0.0f);
        }
    }
    transpose_frags(sw, acc0, lane, ah0, al0);
    transpose_frags(sw, acc1, lane, ah1, al1);

    // layer 2
    load_layer(WF + 8192);
    #pragma unroll
    for (int t = 0; t < 4; ++t) { acc0[t] = (f32x4){0.f,0.f,0.f,0.f}; acc1[t] = (f32x4){0.f,0.f,0.f,0.f}; }
    gemm64_dual_lds(bw, lane, ah0, al0, ah1, al1, acc0, acc1);
    #pragma unroll
    for (int t = 0; t < 4; ++t) {
        float b = b2[t*16 + n];
        #pragma unroll
        for (int r = 0; r < 4; ++r) {
            acc0[t][r] = fmaxf(acc0[t][r] + b, 0.0f);
            acc1[t][r] = fmaxf(acc1[t][r] + b, 0.0f);
        }
    }
    transpose_frags(sw, acc0, lane, ah0, al0);   // a-frags = x2 (tile0)
    transpose_frags(sw, acc1, lane, ah1, al1);   // a-frags = x2 (tile1)

    // scale head (both tiles)
    f32x4 accS0[4], accS1[4];
    load_layer(WF + 2*8192);
    #pragma unroll
    for (int t = 0; t < 4; ++t) { accS0[t] = (f32x4){0.f,0.f,0.f,0.f}; accS1[t] = (f32x4){0.f,0.f,0.f,0.f}; }
    gemm64_dual_lds(bw, lane, ah0, al0, ah1, al1, accS0, accS1);

    // shift head (both tiles)
    f32x4 accH0[4], accH1[4];
    load_layer(WF + 3*8192);
    #pragma unroll
    for (int t = 0; t < 4; ++t) { accH0[t] = (f32x4){0.f,0.f,0.f,0.f}; accH1[t] = (f32x4){0.f,0.f,0.f,0.f}; }
    gemm64_dual_lds(bw, lane, ah0, al0, ah1, al1, accH0, accH1);

    // ---- message + segmented reduce, two passes over 16-row scratch ----
    const int f = lane;
    float s1 = 0.f, s2 = 0.f;
    int prev = auxw[32];                       // dst of first edge in window
    #pragma unroll
    for (int tile = 0; tile < 2; ++tile) {
        const int to = tile * 16;
        f32x4* accS = tile ? accS1 : accS0;
        f32x4* accH = tile ? accH1 : accH0;

        {   // message phase in D-layout registers: lane owns ff=t*16+n, row mg*4+r
            int sn[4];
            #pragma unroll
            for (int r = 0; r < 4; ++r) sn[r] = auxw[to + mg*4 + r];
            #pragma unroll
            for (int t = 0; t < 4; ++t) {
                const int ff = t*16 + n;
                const float bBv = bB[ff];
                const float bCv = bC[ff];
                #pragma unroll
                for (int r = 0; r < 4; ++r) {
                    float vp = Vp[(size_t)sn[r]*DDIM + ff];
                    float sg = 1.0f / (1.0f + __expf(-(accS[t][r] + bBv)));
                    sw[(mg*4 + r)*PADS + ff] = fmaf(sg, vp, accH[t][r] + bCv);
                }
            }
        }
        __builtin_amdgcn_wave_barrier();

        // segmented reduction over this tile's 16 dst-sorted edges (carry across tiles)
        #pragma unroll 4
        for (int e = 0; e < 16; ++e) {
            int dn = auxw[32 + to + e];
            float m1 = sw[e*PADS + f];
            float m2 = m1 * m1;
            if (dn != prev) {
                atomicAdd(&S1[(size_t)prev*DDIM + f], s1);
                atomicAdd(&S2[(size_t)prev*DDIM + f], s2);
                s1 = 0.f; s2 = 0.f; prev = dn;
            }
            s1 += m1; s2 += m2;
        }
        __builtin_amdgcn_wave_barrier();
    }
    atomicAdd(&S1[(size_t)prev*DDIM + f], s1);
    atomicAdd(&S2[(size_t)prev*DDIM + f], s2);
}

// ---------------- finalize ----------------
__global__ __launch_bounds__(256)
void finalize_kernel(const float* __restrict__ S1, const float* __restrict__ S2,
                     const int* __restrict__ degi, float* __restrict__ out)
{
    int gid = blockIdx.x * blockDim.x + threadIdx.x;
    if (gid >= NN*DDIM) return;
    int n = gid >> 6;
    float dn = (float)degi[n];
    dn = dn > 1.0f ? dn : 1.0f;
    float v = (S2[gid] - S1[gid]) / dn;
    out[gid] = sqrtf(fmaxf(v, 0.0f) + EPS_V);
}

extern "C" void kernel_launch(void* const* d_in, const int* in_sizes, int n_in,
                              void* d_out, int out_size, void* d_ws, size_t ws_size,
                              hipStream_t stream) {
    const float* V   = (const float*)d_in[0];
    const float* Eg  = (const float*)d_in[1];
    const int*   src = (const int*)d_in[2];
    const int*   dst = (const int*)d_in[3];
    const float* pAw = (const float*)d_in[4];
    const float* pAb = (const float*)d_in[5];
    const float* pBw = (const float*)d_in[6];
    const float* pBb = (const float*)d_in[7];
    const float* mW1 = (const float*)d_in[8];
    const float* mb1 = (const float*)d_in[9];
    const float* mW2 = (const float*)d_in[10];
    const float* mb2 = (const float*)d_in[11];
    const float* BW  = (const float*)d_in[12];
    const float* Bb  = (const float*)d_in[13];
    const float* CW  = (const float*)d_in[14];
    const float* Cb  = (const float*)d_in[15];
    float* out = (float*)d_out;

    float* ws    = (float*)d_ws;
    float* Vp    = ws;                                   // NN*DDIM f32
    float* S1    = ws + (size_t)NN*DDIM;                 // NN*DDIM f32
    float* S2    = ws + (size_t)2*NN*DDIM;               // NN*DDIM f32
    int*   degi  = (int*)(ws + (size_t)3*NN*DDIM);       // NN i32
    int*   curs  = degi + NN;                            // NN i32
    int*   linc  = curs + NN;                            // NN i32
    int*   bsum  = linc + NN;                            // NB_SCAN i32
    int*   eidx  = bsum + NB_SCAN;                       // NE i32
    short* WF    = (short*)(eidx + NE);                  // 4*8192 shorts (64 KB)

    // zero S1, S2, degi (contiguous)
    hipMemsetAsync(S1, 0, (size_t)(2*NN*DDIM + NN) * sizeof(float), stream);

    prep_w_kernel<<<64, 256, 0, stream>>>(mW1, mW2, BW, CW, WF);
    node_pool_kernel<<<(NN + 63)/64, 256, 0, stream>>>(V, pAw, pAb, pBw, pBb, Vp, dst, degi);
    scan1_kernel<<<NB_SCAN, 256, 0, stream>>>(degi, linc, bsum);
    scan23_kernel<<<NB_SCAN, 256, 0, stream>>>(degi, linc, bsum, curs);
    scatter_kernel<<<(NE + 255)/256, 256, 0, stream>>>(dst, curs, eidx);
    edge_fused_kernel<<<NE/128, 256, 0, stream>>>(Eg, src, dst, eidx, WF,
                                                  mb1, mb2, Bb, Cb, Vp, S1, S2);
    finalize_kernel<<<(NN*DDIM + 255)/256, 256, 0, stream>>>(S1, S2, degi, out);
}

// Round 9
// 485.316 us; speedup vs baseline: 1.2330x; 1.0423x over previous
//
#include <hip/hip_runtime.h>

#define NN 50000
#define NE 800000
#define DDIM 64
#define PADX 68          // fp32 LDS row stride (node pool)
#define PADS 68          // fp32 per-wave scratch stride (rows are 272 B -> 16B aligned, odd*4 banks)
#define NB_SCAN ((NN + 255) / 256)   // 196
#define NPB ((NN + 63) / 64)         // 782 node-pool blocks
#define NEG_SLOPE 0.2f
#define EPS_V 1e-5f

typedef short bf16x8 __attribute__((ext_vector_type(8)));
typedef float f32x4 __attribute__((ext_vector_type(4)));

__device__ __forceinline__ float lrelu_f(float x) { return x >= 0.0f ? x : NEG_SLOPE * x; }

__device__ __forceinline__ unsigned short bf16_rn(float x) {
    union { float f; unsigned int u; } c; c.f = x;
    unsigned int r = c.u + 0x7FFF + ((c.u >> 16) & 1);
    return (unsigned short)(r >> 16);
}
__device__ __forceinline__ float bf16_tof(unsigned short h) {
    union { float f; unsigned int u; } c; c.u = ((unsigned int)h) << 16;
    return c.f;
}

// packed bf16 convert (RNE), 2 f32 -> u32 [lo=bf16(a) | hi=bf16(b)]
__device__ __forceinline__ unsigned cvtpk_bf16(float a, float b) {
    unsigned r;
    asm("v_cvt_pk_bf16_f32 %0, %1, %2" : "=v"(r) : "v"(a), "v"(b));
    return r;
}

// split 8 fp32 -> hi/lo bf16x8 (RNE both; ~2^-18 effective rel err) via v_cvt_pk_bf16_f32
__device__ __forceinline__ void split8(const float* __restrict__ v, bf16x8& h, bf16x8& l)
{
    union { bf16x8 v8; unsigned u[4]; } H, L;
    #pragma unroll
    for (int k = 0; k < 4; ++k) {
        float a = v[2*k], b = v[2*k+1];
        unsigned p = cvtpk_bf16(a, b);
        union { float f; unsigned u; } h0, h1;
        h0.u = p << 16;
        h1.u = p & 0xFFFF0000u;
        unsigned q = cvtpk_bf16(a - h0.f, b - h1.f);
        H.u[k] = p;
        L.u[k] = q;
    }
    h = H.v8; l = L.v8;
}

// ---------------- fp32 micro-tile GEMM helpers (node pooling only) ----------------
__device__ __forceinline__ void mma_tile(float acc[16], const float* __restrict__ XT,
                                         const float* __restrict__ Wc, int e0, int f0)
{
    #pragma unroll 4
    for (int kk = 0; kk < DDIM; kk += 4) {
        float4 A0 = *(const float4*)&XT[(kk+0)*PADX + e0];
        float4 A1 = *(const float4*)&XT[(kk+1)*PADX + e0];
        float4 A2 = *(const float4*)&XT[(kk+2)*PADX + e0];
        float4 A3 = *(const float4*)&XT[(kk+3)*PADX + e0];
        float4 B0 = *(const float4*)&Wc[(f0+0)*PADX + kk];
        float4 B1 = *(const float4*)&Wc[(f0+1)*PADX + kk];
        float4 B2 = *(const float4*)&Wc[(f0+2)*PADX + kk];
        float4 B3 = *(const float4*)&Wc[(f0+3)*PADX + kk];
        const float a[4][4] = {{A0.x,A0.y,A0.z,A0.w},{A1.x,A1.y,A1.z,A1.w},
                               {A2.x,A2.y,A2.z,A2.w},{A3.x,A3.y,A3.z,A3.w}};
        const float b[4][4] = {{B0.x,B0.y,B0.z,B0.w},{B1.x,B1.y,B1.z,B1.w},
                               {B2.x,B2.y,B2.z,B2.w},{B3.x,B3.y,B3.z,B3.w}};
        #pragma unroll
        for (int j = 0; j < 4; ++j)
            #pragma unroll
            for (int i = 0; i < 4; ++i)
                #pragma unroll
                for (int q = 0; q < 4; ++q)
                    acc[i*4+j] = fmaf(a[q][i], b[j][q], acc[i*4+j]);
    }
}

__device__ __forceinline__ void load_w_f32(float* __restrict__ Wc, const float* __restrict__ Wg, int tid)
{
    #pragma unroll
    for (int c = 0; c < 4; ++c) {
        int idx = (c << 10) + (tid << 2);
        int f = idx >> 6, k = idx & 63;
        *(float4*)&Wc[f*PADX + k] = *(const float4*)&Wg[idx];
    }
}

// ---------------- node pooling (fp32) + prep_w (merged) + dst histogram ----------------
// Blocks [0, NPB): node pooling. Blocks [NPB, NPB+64): split-bf16 weight fragment
// precompute (WF). All blocks share the edge-histogram grid-stride tail.
__global__ __launch_bounds__(256, 3)
void node_pool_kernel(const float* __restrict__ V,
                      const float* __restrict__ Aw, const float* __restrict__ Ab,
                      const float* __restrict__ Bw, const float* __restrict__ Bbv,
                      float* __restrict__ Vp,
                      const int* __restrict__ dst, int* __restrict__ degi,
                      const float* __restrict__ W1, const float* __restrict__ W2,
                      const float* __restrict__ WB, const float* __restrict__ WC,
                      short* __restrict__ WF)
{
    __shared__ float Wc[DDIM*PADX];
    __shared__ float XT[DDIM*PADX];
    const int tid = threadIdx.x;

    if (blockIdx.x >= NPB) {
        // ---- prep_w path: WF[L][t][ks][hl][lane][j]; per-layer stride 8192 shorts ----
        int gid = (blockIdx.x - NPB) * 256 + tid;    // 64 blocks -> 16384 threads
        int L = gid >> 12, r = gid & 4095;
        int t = r >> 10, ks = (r >> 9) & 1, lane = (r >> 3) & 63, j = r & 7;
        const float* Ws = (L == 0) ? W1 : (L == 1) ? W2 : (L == 2) ? WB : WC;
        int n = lane & 15, kg = lane >> 4;
        int f = t*16 + n, k = ks*32 + kg*8 + j;
        float v = Ws[f*64 + k];
        unsigned short h = bf16_rn(v);
        unsigned short l = bf16_rn(v - bf16_tof(h));
        int base = L*8192 + ((t*2 + ks)*2)*512 + lane*8 + j;
        WF[base]       = (short)h;
        WF[base + 512] = (short)l;

        const int stride = gridDim.x * 256;
        for (int e = blockIdx.x * 256 + tid; e < NE; e += stride)
            atomicAdd(&degi[dst[e]], 1);
        return;
    }

    const int nb = blockIdx.x * 64;
    const int e0 = (tid & 15) << 2;
    const int f0 = (tid >> 4) << 2;

    #pragma unroll
    for (int c = 0; c < 4; ++c) {
        int idx = (c << 10) + (tid << 2);
        int e = idx >> 6, d = idx & 63;
        int row = nb + e; if (row > NN-1) row = NN-1;
        float4 v = *(const float4*)&V[(size_t)row*DDIM + d];
        XT[(d+0)*PADX + e] = lrelu_f(v.x);
        XT[(d+1)*PADX + e] = lrelu_f(v.y);
        XT[(d+2)*PADX + e] = lrelu_f(v.z);
        XT[(d+3)*PADX + e] = lrelu_f(v.w);
    }
    load_w_f32(Wc, Aw, tid);
    __syncthreads();

    float acc[16];
    #pragma unroll
    for (int i = 0; i < 16; ++i) acc[i] = 0.f;
    mma_tile(acc, XT, Wc, e0, f0);
    __syncthreads();

    {   // lrelu(acc + Ab) -> XT
        float4 bv = *(const float4*)&Ab[f0];
        const float ba[4] = {bv.x, bv.y, bv.z, bv.w};
        #pragma unroll
        for (int j = 0; j < 4; ++j) {
            float4 v;
            v.x = lrelu_f(acc[0*4+j] + ba[j]);
            v.y = lrelu_f(acc[1*4+j] + ba[j]);
            v.z = lrelu_f(acc[2*4+j] + ba[j]);
            v.w = lrelu_f(acc[3*4+j] + ba[j]);
            *(float4*)&XT[(f0+j)*PADX + e0] = v;
        }
    }
    load_w_f32(Wc, Bw, tid);
    __syncthreads();

    float acc2[16];
    #pragma unroll
    for (int i = 0; i < 16; ++i) acc2[i] = 0.f;
    mma_tile(acc2, XT, Wc, e0, f0);

    float4 bv = *(const float4*)&Bbv[f0];
    #pragma unroll
    for (int i = 0; i < 4; ++i) {
        int row = nb + e0 + i;
        if (row < NN) {
            float4 o;
            o.x = acc2[i*4+0] + bv.x;
            o.y = acc2[i*4+1] + bv.y;
            o.z = acc2[i*4+2] + bv.z;
            o.w = acc2[i*4+3] + bv.w;
            *(float4*)&Vp[(size_t)row*DDIM + f0] = o;
        }
    }

    // fused histogram tail: grid-stride over edges
    const int stride = gridDim.x * 256;
    for (int e = blockIdx.x * 256 + tid; e < NE; e += stride)
        atomicAdd(&degi[dst[e]], 1);
}

// ---------------- CSR build: scan / scatter ----------------
__global__ __launch_bounds__(256)
void scan1_kernel(const int* __restrict__ degi, int* __restrict__ linc, int* __restrict__ bsum)
{
    __shared__ int ws[4];
    const int tid = threadIdx.x;
    const int lane = tid & 63, wv = tid >> 6;
    int i = blockIdx.x * 256 + tid;
    int v = (i < NN) ? degi[i] : 0;
    int sc = v;
    #pragma unroll
    for (int off = 1; off < 64; off <<= 1) {
        int t = __shfl_up(sc, off, 64);
        if (lane >= off) sc += t;
    }
    if (lane == 63) ws[wv] = sc;
    __syncthreads();
    int wb = 0;
    #pragma unroll
    for (int w = 0; w < 4; ++w) if (w < wv) wb += ws[w];
    int incl = sc + wb;
    if (i < NN) linc[i] = incl;
    if (tid == 255) bsum[blockIdx.x] = incl;
}

__global__ __launch_bounds__(256)
void scan23_kernel(const int* __restrict__ degi, const int* __restrict__ linc,
                   const int* __restrict__ bsum, int* __restrict__ curs)
{
    __shared__ int ws[4];
    __shared__ int base_s;
    const int tid = threadIdx.x;
    const int lane = tid & 63, wv = tid >> 6;
    int v = (tid < NB_SCAN) ? bsum[tid] : 0;
    int sc = v;
    #pragma unroll
    for (int off = 1; off < 64; off <<= 1) {
        int t = __shfl_up(sc, off, 64);
        if (lane >= off) sc += t;
    }
    if (lane == 63) ws[wv] = sc;
    __syncthreads();
    int wb = 0;
    #pragma unroll
    for (int w = 0; w < 4; ++w) if (w < wv) wb += ws[w];
    if (tid == blockIdx.x) base_s = sc + wb - v;
    __syncthreads();
    int i = blockIdx.x * 256 + tid;
    if (i < NN) curs[i] = base_s + linc[i] - degi[i];
}

// scatter: build dst-sorted edge list eidx
__global__ __launch_bounds__(256)
void scatter_kernel(const int* __restrict__ dst, int* __restrict__ cursor, int* __restrict__ eidx)
{
    int e = blockIdx.x * 256 + threadIdx.x;
    if (e < NE) {
        int p = atomicAdd(&cursor[dst[e]], 1);
        eidx[p] = e;
    }
}

// ---------------- fused dst-sorted split-bf16 MFMA edge kernel ----------------
// Dual-tile GEMM with B-fragments in LDS (bw): loaded once per block per layer,
// read via ds_read_b128 instead of per-wave L2 traffic (6x L2 cut).
__device__ __forceinline__ void gemm64_dual_lds(const short* bw, int lane,
                                                const bf16x8 ah0[2], const bf16x8 al0[2],
                                                const bf16x8 ah1[2], const bf16x8 al1[2],
                                                f32x4 acc0[4], f32x4 acc1[4])
{
    #pragma unroll
    for (int ks = 0; ks < 2; ++ks) {
        bf16x8 bh[4], bl[4];
        #pragma unroll
        for (int t = 0; t < 4; ++t) {
            bh[t] = *(const bf16x8*)&bw[(((t*2 + ks)*2 + 0)*64 + lane)*8];
            bl[t] = *(const bf16x8*)&bw[(((t*2 + ks)*2 + 1)*64 + lane)*8];
        }
        #pragma unroll
        for (int t = 0; t < 4; ++t) {
            acc0[t] = __builtin_amdgcn_mfma_f32_16x16x32_bf16(al0[ks], bh[t], acc0[t], 0, 0, 0);
            acc1[t] = __builtin_amdgcn_mfma_f32_16x16x32_bf16(al1[ks], bh[t], acc1[t], 0, 0, 0);
            acc0[t] = __builtin_amdgcn_mfma_f32_16x16x32_bf16(ah0[ks], bl[t], acc0[t], 0, 0, 0);
            acc1[t] = __builtin_amdgcn_mfma_f32_16x16x32_bf16(ah1[ks], bl[t], acc1[t], 0, 0, 0);
            acc0[t] = __builtin_amdgcn_mfma_f32_16x16x32_bf16(ah0[ks], bh[t], acc0[t], 0, 0, 0);
            acc1[t] = __builtin_amdgcn_mfma_f32_16x16x32_bf16(ah1[ks], bh[t], acc1[t], 0, 0, 0);
        }
    }
}

// Single-tile transpose through a 16-row per-wave LDS tile (reused sequentially;
// per-wave LDS ops are in-order, wave_barrier fences compiler reordering).
__device__ __forceinline__ void transpose_frags(float* __restrict__ sw, const f32x4 y[4],
                                                int lane, bf16x8 ah[2], bf16x8 al[2])
{
    const int n = lane & 15, mg = lane >> 4;
    #pragma unroll
    for (int t = 0; t < 4; ++t)
        #pragma unroll
        for (int r = 0; r < 4; ++r)
            sw[(mg*4 + r)*PADS + t*16 + n] = y[t][r];
    __builtin_amdgcn_wave_barrier();
    const int m = lane & 15, kg = lane >> 4;   // m: edge row, kg: k-group
    float x[16];
    *(float4*)&x[0]  = *(const float4*)&sw[m*PADS + kg*8];
    *(float4*)&x[4]  = *(const float4*)&sw[m*PADS + kg*8 + 4];
    *(float4*)&x[8]  = *(const float4*)&sw[m*PADS + 32 + kg*8];
    *(float4*)&x[12] = *(const float4*)&sw[m*PADS + 32 + kg*8 + 4];
    split8(&x[0], ah[0], al[0]);
    split8(&x[8], ah[1], al[1]);
    __builtin_amdgcn_wave_barrier();
}

// Fused edge kernel: dst-sorted eidx gather -> MLP (bw in LDS, async-staged) -> heads
// -> message -> per-wave segmented reduce with carry -> atomicAdd at segment closes.
// Weight staging is issue-early (global->reg) / commit-late (reg->LDS): each layer's
// L2 latency hides under the previous layer's MFMA cluster.
__global__ __launch_bounds__(256, 3)
void edge_fused_kernel(const float* __restrict__ Eg,
                       const int* __restrict__ src, const int* __restrict__ dst,
                       const int* __restrict__ eidx,
                       const short* __restrict__ WF,
                       const float* __restrict__ b1, const float* __restrict__ b2,
                       const float* __restrict__ bB, const float* __restrict__ bC,
                       const float* __restrict__ Vp,
                       float* __restrict__ S1, float* __restrict__ S2)
{
    __shared__ __align__(16) short bw[8192];   // current layer's B fragments (16384 B)
    __shared__ float scratch[4 * 16 * PADS];   // per-wave 16x68 fp32 tile (17408 B)
    __shared__ int aux[4 * 64];                // per-wave: [0..31]=src, [32..63]=dst

    const int tid = threadIdx.x;
    const int lane = tid & 63, wv = tid >> 6;
    float* sw = scratch + wv * 16 * PADS;
    int* auxw = aux + wv * 64;

    const int ew = blockIdx.x * 128 + wv * 32;  // this wave's 32 edges (dst-sorted)
    const int m = lane & 15, kg = lane >> 4;
    const int n = lane & 15, mg = lane >> 4;

    uint4 w0, w1, w2, w3;                      // in-flight weight stage (16 VGPRs)
    #define ISSUE_W(Wg) do { const uint4* s_ = (const uint4*)(Wg); \
        w0 = s_[tid]; w1 = s_[256 + tid]; w2 = s_[512 + tid]; w3 = s_[768 + tid]; } while (0)
    #define COMMIT_W() do { __syncthreads(); uint4* d_ = (uint4*)bw; \
        d_[tid] = w0; d_[256 + tid] = w1; d_[512 + tid] = w2; d_[768 + tid] = w3; \
        __syncthreads(); } while (0)

    ISSUE_W(WF);                               // layer-1 loads fly during E staging

    if (lane < 32) {
        int eg = eidx[ew + lane];
        auxw[lane]      = src[eg];
        auxw[32 + lane] = dst[eg];
    }
    // A-fragments from gathered E rows (256B-row gather, 4 full lines each)
    bf16x8 ah0[2], al0[2], ah1[2], al1[2];
    {
        int eg0 = eidx[ew + m];
        int eg1 = eidx[ew + 16 + m];
        const float* er0 = Eg + (size_t)eg0*DDIM + kg*8;
        const float* er1 = Eg + (size_t)eg1*DDIM + kg*8;
        float x[16];
        *(float4*)&x[0]  = *(const float4*)&er0[0];
        *(float4*)&x[4]  = *(const float4*)&er0[4];
        *(float4*)&x[8]  = *(const float4*)&er0[32];
        *(float4*)&x[12] = *(const float4*)&er0[36];
        split8(&x[0], ah0[0], al0[0]);
        split8(&x[8], ah0[1], al0[1]);
        *(float4*)&x[0]  = *(const float4*)&er1[0];
        *(float4*)&x[4]  = *(const float4*)&er1[4];
        *(float4*)&x[8]  = *(const float4*)&er1[32];
        *(float4*)&x[12] = *(const float4*)&er1[36];
        split8(&x[0], ah1[0], al1[0]);
        split8(&x[8], ah1[1], al1[1]);
    }

    // layer 1
    COMMIT_W();
    ISSUE_W(WF + 8192);                        // layer-2 loads fly under layer-1 MFMAs
    f32x4 acc0[4], acc1[4];
    #pragma unroll
    for (int t = 0; t < 4; ++t) { acc0[t] = (f32x4){0.f,0.f,0.f,0.f}; acc1[t] = (f32x4){0.f,0.f,0.f,0.f}; }
    __builtin_amdgcn_s_setprio(1);
    gemm64_dual_lds(bw, lane, ah0, al0, ah1, al1, acc0, acc1);
    __builtin_amdgcn_s_setprio(0);
    #pragma unroll
    for (int t = 0; t < 4; ++t) {
        float b = b1[t*16 + n];
        #pragma unroll
        for (int r = 0; r < 4; ++r) {
            acc0[t][r] = fmaxf(acc0[t][r] + b, 0.0f);
            acc1[t][r] = fmaxf(acc1[t][r] + b, 0.0f);
        }
    }
    transpose_frags(sw, acc0, lane, ah0, al0);
    transpose_frags(sw, acc1, lane, ah1, al1);

    // layer 2
    COMMIT_W();
    ISSUE_W(WF + 2*8192);                      // scale-head loads fly under layer-2 MFMAs
    #pragma unroll
    for (int t = 0; t < 4; ++t) { acc0[t] = (f32x4){0.f,0.f,0.f,0.f}; acc1[t] = (f32x4){0.f,0.f,0.f,0.f}; }
    __builtin_amdgcn_s_setprio(1);
    gemm64_dual_lds(bw, lane, ah0, al0, ah1, al1, acc0, acc1);
    __builtin_amdgcn_s_setprio(0);
    #pragma unroll
    for (int t = 0; t < 4; ++t) {
        float b = b2[t*16 + n];
        #pragma unroll
        for (int r = 0; r < 4; ++r) {
            acc0[t][r] = fmaxf(acc0[t][r] + b, 0.0f);
            acc1[t][r] = fmaxf(acc1[t][r] + b, 0.0f);
        }
    }
    transpose_frags(sw, acc0, lane, ah0, al0);   // a-frags = x2 (tile0)
    transpose_frags(sw, acc1, lane, ah1, al1);   // a-frags = x2 (tile1)

    // scale head (both tiles)
    COMMIT_W();
    ISSUE_W(WF + 3*8192);                      // shift-head loads fly under scale MFMAs
    f32x4 accS0[4], accS1[4];
    #pragma unroll
    for (int t = 0; t < 4; ++t) { accS0[t] = (f32x4){0.f,0.f,0.f,0.f}; accS1[t] = (f32x4){0.f,0.f,0.f,0.f}; }
    __builtin_amdgcn_s_setprio(1);
    gemm64_dual_lds(bw, lane, ah0, al0, ah1, al1, accS0, accS1);
    __builtin_amdgcn_s_setprio(0);

    // shift head (both tiles)
    COMMIT_W();
    f32x4 accH0[4], accH1[4];
    #pragma unroll
    for (int t = 0; t < 4; ++t) { accH0[t] = (f32x4){0.f,0.f,0.f,0.f}; accH1[t] = (f32x4){0.f,0.f,0.f,0.f}; }
    __builtin_amdgcn_s_setprio(1);
    gemm64_dual_lds(bw, lane, ah0, al0, ah1, al1, accH0, accH1);
    __builtin_amdgcn_s_setprio(0);

    // ---- message + segmented reduce, two passes over 16-row scratch ----
    const int f = lane;
    float s1 = 0.f, s2 = 0.f;
    int prev = auxw[32];                       // dst of first edge in window
    #pragma unroll
    for (int tile = 0; tile < 2; ++tile) {
        const int to = tile * 16;
        f32x4* accS = tile ? accS1 : accS0;
        f32x4* accH = tile ? accH1 : accH0;

        {   // message phase in D-layout registers: lane owns ff=t*16+n, row mg*4+r
            int sn[4];
            #pragma unroll
            for (int r = 0; r < 4; ++r) sn[r] = auxw[to + mg*4 + r];
            #pragma unroll
            for (int t = 0; t < 4; ++t) {
                const int ff = t*16 + n;
                const float bBv = bB[ff];
                const float bCv = bC[ff];
                #pragma unroll
                for (int r = 0; r < 4; ++r) {
                    float vp = Vp[(size_t)sn[r]*DDIM + ff];
                    float sg = 1.0f / (1.0f + __expf(-(accS[t][r] + bBv)));
                    sw[(mg*4 + r)*PADS + ff] = fmaf(sg, vp, accH[t][r] + bCv);
                }
            }
        }
        __builtin_amdgcn_wave_barrier();

        // segmented reduction over this tile's 16 dst-sorted edges (carry across tiles)
        #pragma unroll 4
        for (int e = 0; e < 16; ++e) {
            int dn = auxw[32 + to + e];
            float m1 = sw[e*PADS + f];
            float m2 = m1 * m1;
            if (dn != prev) {
                atomicAdd(&S1[(size_t)prev*DDIM + f], s1);
                atomicAdd(&S2[(size_t)prev*DDIM + f], s2);
                s1 = 0.f; s2 = 0.f; prev = dn;
            }
            s1 += m1; s2 += m2;
        }
        __builtin_amdgcn_wave_barrier();
    }
    atomicAdd(&S1[(size_t)prev*DDIM + f], s1);
    atomicAdd(&S2[(size_t)prev*DDIM + f], s2);
    #undef ISSUE_W
    #undef COMMIT_W
}

// ---------------- finalize ----------------
__global__ __launch_bounds__(256)
void finalize_kernel(const float* __restrict__ S1, const float* __restrict__ S2,
                     const int* __restrict__ degi, float* __restrict__ out)
{
    int gid = blockIdx.x * blockDim.x + threadIdx.x;
    if (gid >= NN*DDIM) return;
    int n = gid >> 6;
    float dn = (float)degi[n];
    dn = dn > 1.0f ? dn : 1.0f;
    float v = (S2[gid] - S1[gid]) / dn;
    out[gid] = sqrtf(fmaxf(v, 0.0f) + EPS_V);
}

extern "C" void kernel_launch(void* const* d_in, const int* in_sizes, int n_in,
                              void* d_out, int out_size, void* d_ws, size_t ws_size,
                              hipStream_t stream) {
    const float* V   = (const float*)d_in[0];
    const float* Eg  = (const float*)d_in[1];
    const int*   src = (const int*)d_in[2];
    const int*   dst = (const int*)d_in[3];
    const float* pAw = (const float*)d_in[4];
    const float* pAb = (const float*)d_in[5];
    const float* pBw = (const float*)d_in[6];
    const float* pBb = (const float*)d_in[7];
    const float* mW1 = (const float*)d_in[8];
    const float* mb1 = (const float*)d_in[9];
    const float* mW2 = (const float*)d_in[10];
    const float* mb2 = (const float*)d_in[11];
    const float* BW  = (const float*)d_in[12];
    const float* Bb  = (const float*)d_in[13];
    const float* CW  = (const float*)d_in[14];
    const float* Cb  = (const float*)d_in[15];
    float* out = (float*)d_out;

    float* ws    = (float*)d_ws;
    float* Vp    = ws;                                   // NN*DDIM f32
    float* S1    = ws + (size_t)NN*DDIM;                 // NN*DDIM f32
    float* S2    = ws + (size_t)2*NN*DDIM;               // NN*DDIM f32
    int*   degi  = (int*)(ws + (size_t)3*NN*DDIM);       // NN i32
    int*   curs  = degi + NN;                            // NN i32
    int*   linc  = curs + NN;                            // NN i32
    int*   bsum  = linc + NN;                            // NB_SCAN i32
    int*   eidx  = bsum + NB_SCAN;                       // NE i32
    short* WF    = (short*)(eidx + NE);                  // 4*8192 shorts (64 KB)

    // zero S1, S2, degi (contiguous)
    hipMemsetAsync(S1, 0, (size_t)(2*NN*DDIM + NN) * sizeof(float), stream);

    node_pool_kernel<<<NPB + 64, 256, 0, stream>>>(V, pAw, pAb, pBw, pBb, Vp, dst, degi,
                                                   mW1, mW2, BW, CW, WF);
    scan1_kernel<<<NB_SCAN, 256, 0, stream>>>(degi, linc, bsum);
    scan23_kernel<<<NB_SCAN, 256, 0, stream>>>(degi, linc, bsum, curs);
    scatter_kernel<<<(NE + 255)/256, 256, 0, stream>>>(dst, curs, eidx);
    edge_fused_kernel<<<NE/128, 256, 0, stream>>>(Eg, src, dst, eidx, WF,
                                                  mb1, mb2, Bb, Cb, Vp, S1, S2);
    finalize_kernel<<<(NN*DDIM + 255)/256, 256, 0, stream>>>(S1, S2, degi, out);
}